// Round 6
// baseline (9046.356 us; speedup 1.0000x reference)
//
#include <hip/hip_runtime.h>
#include <math.h>

// ---------------------------------------------------------------------------
// Mamba1 audio model forward, fp32 (round 5: resubmit — rounds 1-4 never ran,
// GPU acquisition timeouts; holding experiment fixed until first real datum).
// Conv stack runs per-batch-element (4 passes) with pool fused into the 2nd
// conv of each block; block-4 pool writes the transposed (B*T,1792) features
// directly. Peak workspace ~127 MB.
// ---------------------------------------------------------------------------

static __device__ __forceinline__ float sigmoidf_(float x) {
  return 1.f / (1.f + __expf(-x));
}

// ---------------- conv3x3 SAME + BN(eval: var=1) + ReLU --------------------
// Single batch element. in [CIN][T][F], W [COUT][CIN][3][3], out [COUT][T][F].
template<int CIN, int COUT, int F, int CI_TILE, int F_TH, int CO_PER_TH>
__global__ __launch_bounds__(256)
void conv3x3_bn_relu(const float* __restrict__ in, const float* __restrict__ Wt,
                     const float* __restrict__ gam, const float* __restrict__ bet,
                     float* __restrict__ out)
{
  constexpr int T = 1000;
  constexpr int CO_TH = 256 / F_TH;
  constexpr int CO_TILE = CO_TH * CO_PER_TH;
  constexpr int NF = (F + F_TH - 1) / F_TH;
  constexpr int FW = NF * F_TH + 2;               // zero-padded row width
  static_assert(256 % F_TH == 0, "");
  static_assert(COUT % CO_TILE == 0, "");
  static_assert(CIN % CI_TILE == 0, "");

  __shared__ float in_s[CI_TILE][3][FW];
  __shared__ float w_s[CO_TILE][CI_TILE * 9 + 1];

  const int tid  = threadIdx.x;
  const int t    = blockIdx.y;
  const int co0  = blockIdx.x * CO_TILE;
  const int f_l  = tid % F_TH;
  const int co_l = (tid / F_TH) * CO_PER_TH;

  float acc[CO_PER_TH][NF];
  #pragma unroll
  for (int c = 0; c < CO_PER_TH; ++c)
    #pragma unroll
    for (int nf = 0; nf < NF; ++nf) acc[c][nf] = 0.f;

  for (int ci0 = 0; ci0 < CIN; ci0 += CI_TILE) {
    __syncthreads();
    constexpr int IN_ELEMS = CI_TILE * 3 * FW;
    for (int i = tid; i < IN_ELEMS; i += 256) {
      int x  = i % FW;
      int rc = i / FW;
      int r  = rc % 3;
      int ci = rc / 3;
      int fi = x - 1;
      int ti = t + r - 1;
      float v = 0.f;
      if (fi >= 0 && fi < F && ti >= 0 && ti < T)
        v = in[((size_t)(ci0 + ci) * T + ti) * F + fi];
      in_s[ci][r][x] = v;
    }
    constexpr int W_ELEMS = CO_TILE * CI_TILE * 9;
    for (int i = tid; i < W_ELEMS; i += 256) {
      int k    = i % 9;
      int rest = i / 9;
      int ci   = rest % CI_TILE;
      int co   = rest / CI_TILE;
      w_s[co][ci * 9 + k] =
          Wt[(((size_t)(co0 + co)) * CIN + (ci0 + ci)) * 9 + k];
    }
    __syncthreads();
    #pragma unroll
    for (int ci = 0; ci < CI_TILE; ++ci) {
      #pragma unroll
      for (int ky = 0; ky < 3; ++ky) {
        #pragma unroll
        for (int kx = 0; kx < 3; ++kx) {
          float w[CO_PER_TH];
          #pragma unroll
          for (int c = 0; c < CO_PER_TH; ++c)
            w[c] = w_s[co_l + c][ci * 9 + ky * 3 + kx];
          #pragma unroll
          for (int nf = 0; nf < NF; ++nf) {
            float v = in_s[ci][ky][f_l + nf * F_TH + kx];
            #pragma unroll
            for (int c = 0; c < CO_PER_TH; ++c)
              acc[c][nf] = fmaf(w[c], v, acc[c][nf]);
          }
        }
      }
    }
  }
  const float inv = rsqrtf(1.f + 1e-5f);
  #pragma unroll
  for (int c = 0; c < CO_PER_TH; ++c) {
    int co = co0 + co_l + c;
    float sc = gam[co] * inv;
    float bi = bet[co];
    #pragma unroll
    for (int nf = 0; nf < NF; ++nf) {
      int f = f_l + nf * F_TH;
      if (f < F)
        out[((size_t)co * T + t) * F + f] =
            fmaxf(fmaf(acc[c][nf], sc, bi), 0.f);
    }
  }
}

// -------- conv3x3 + BN + ReLU + avgpool2(F) fused (single batch elem) ------
// If TRANS: writes out[t*1792 + co*14 + fo] (block-4 feature layout),
// else out[(co*T + t)*Fo + fo].
template<int CIN, int COUT, int F, int CI_TILE, int FO_TH, int CO_PER_TH, bool TRANS>
__global__ __launch_bounds__(256)
void conv3x3_pool_bn_relu(const float* __restrict__ in, const float* __restrict__ Wt,
                          const float* __restrict__ gam, const float* __restrict__ bet,
                          float* __restrict__ out)
{
  constexpr int T = 1000;
  constexpr int Fo = F / 2;
  constexpr int NFO = (Fo + FO_TH - 1) / FO_TH;
  constexpr int FWP = 2 * NFO * FO_TH + 2;
  constexpr int CO_TH = 256 / FO_TH;
  constexpr int CO_TILE = CO_TH * CO_PER_TH;
  static_assert(256 % FO_TH == 0, "");
  static_assert(COUT % CO_TILE == 0, "");
  static_assert(CIN % CI_TILE == 0, "");

  __shared__ float in_s[CI_TILE][3][FWP];
  __shared__ float w_s[CO_TILE][CI_TILE * 9 + 1];

  const int tid  = threadIdx.x;
  const int t    = blockIdx.y;
  const int co0  = blockIdx.x * CO_TILE;
  const int fo_l = tid % FO_TH;
  const int co_l = (tid / FO_TH) * CO_PER_TH;

  float acc0[CO_PER_TH][NFO], acc1[CO_PER_TH][NFO];
  #pragma unroll
  for (int c = 0; c < CO_PER_TH; ++c)
    #pragma unroll
    for (int nf = 0; nf < NFO; ++nf) { acc0[c][nf] = 0.f; acc1[c][nf] = 0.f; }

  for (int ci0 = 0; ci0 < CIN; ci0 += CI_TILE) {
    __syncthreads();
    constexpr int IN_ELEMS = CI_TILE * 3 * FWP;
    for (int i = tid; i < IN_ELEMS; i += 256) {
      int x  = i % FWP;
      int rc = i / FWP;
      int r  = rc % 3;
      int ci = rc / 3;
      int fi = x - 1;
      int ti = t + r - 1;
      float v = 0.f;
      if (fi >= 0 && fi < F && ti >= 0 && ti < T)
        v = in[((size_t)(ci0 + ci) * T + ti) * F + fi];
      in_s[ci][r][x] = v;
    }
    constexpr int W_ELEMS = CO_TILE * CI_TILE * 9;
    for (int i = tid; i < W_ELEMS; i += 256) {
      int k    = i % 9;
      int rest = i / 9;
      int ci   = rest % CI_TILE;
      int co   = rest / CI_TILE;
      w_s[co][ci * 9 + k] =
          Wt[(((size_t)(co0 + co)) * CIN + (ci0 + ci)) * 9 + k];
    }
    __syncthreads();
    #pragma unroll
    for (int ci = 0; ci < CI_TILE; ++ci) {
      #pragma unroll
      for (int ky = 0; ky < 3; ++ky) {
        #pragma unroll
        for (int kx = 0; kx < 3; ++kx) {
          float w[CO_PER_TH];
          #pragma unroll
          for (int c = 0; c < CO_PER_TH; ++c)
            w[c] = w_s[co_l + c][ci * 9 + ky * 3 + kx];
          #pragma unroll
          for (int nf = 0; nf < NFO; ++nf) {
            int xb = 2 * (fo_l + nf * FO_TH) + kx;
            float v0 = in_s[ci][ky][xb];
            float v1 = in_s[ci][ky][xb + 1];
            #pragma unroll
            for (int c = 0; c < CO_PER_TH; ++c) {
              acc0[c][nf] = fmaf(w[c], v0, acc0[c][nf]);
              acc1[c][nf] = fmaf(w[c], v1, acc1[c][nf]);
            }
          }
        }
      }
    }
  }
  const float inv = rsqrtf(1.f + 1e-5f);
  #pragma unroll
  for (int c = 0; c < CO_PER_TH; ++c) {
    int co = co0 + co_l + c;
    float sc = gam[co] * inv;
    float bi = bet[co];
    #pragma unroll
    for (int nf = 0; nf < NFO; ++nf) {
      int fo = fo_l + nf * FO_TH;
      if (fo < Fo) {
        float a = fmaxf(fmaf(acc0[c][nf], sc, bi), 0.f);
        float bvl = fmaxf(fmaf(acc1[c][nf], sc, bi), 0.f);
        float v = 0.5f * (a + bvl);
        if (TRANS)
          out[(size_t)t * 1792 + co * 14 + fo] = v;
        else
          out[((size_t)co * T + t) * Fo + fo] = v;
      }
    }
  }
}

// ---------------- generic tiled fp32 GEMM: C[M,N] = A[M,K] * W[N,K]^T ------
// EPI: 0 none; 1 relu(v*sc[n]/sqrt(1+eps)+bi[n]); 2 softplus(v+bi[n]);
//      3 sigmoid(v+bi[n]).   Requires K % 16 == 0.
template<int EPI>
__global__ __launch_bounds__(256)
void gemm_nt(const float* __restrict__ A, int lda,
             const float* __restrict__ W,
             float* __restrict__ C, int M, int N, int K,
             const float* __restrict__ sc, const float* __restrict__ bi)
{
  __shared__ float As[16][68];
  __shared__ float Bs[16][68];
  const int tid = threadIdx.x;
  const int m0 = blockIdx.y * 64, n0 = blockIdx.x * 64;
  const int tx = tid % 16, ty = tid / 16;
  const int lr = tid / 4, lk = (tid % 4) * 4;
  float acc[4][4];
  #pragma unroll
  for (int i = 0; i < 4; ++i)
    #pragma unroll
    for (int j = 0; j < 4; ++j) acc[i][j] = 0.f;

  for (int k0 = 0; k0 < K; k0 += 16) {
    __syncthreads();
    {
      int m = m0 + lr;
      float4 a = make_float4(0.f, 0.f, 0.f, 0.f);
      if (m < M) a = *(const float4*)(A + (size_t)m * lda + k0 + lk);
      As[lk + 0][lr] = a.x; As[lk + 1][lr] = a.y;
      As[lk + 2][lr] = a.z; As[lk + 3][lr] = a.w;
      int n = n0 + lr;
      float4 w = make_float4(0.f, 0.f, 0.f, 0.f);
      if (n < N) w = *(const float4*)(W + (size_t)n * K + k0 + lk);
      Bs[lk + 0][lr] = w.x; Bs[lk + 1][lr] = w.y;
      Bs[lk + 2][lr] = w.z; Bs[lk + 3][lr] = w.w;
    }
    __syncthreads();
    #pragma unroll
    for (int kk = 0; kk < 16; ++kk) {
      float4 av = *(const float4*)(&As[kk][ty * 4]);
      float4 bv = *(const float4*)(&Bs[kk][tx * 4]);
      float a[4] = {av.x, av.y, av.z, av.w};
      float bb[4] = {bv.x, bv.y, bv.z, bv.w};
      #pragma unroll
      for (int i = 0; i < 4; ++i)
        #pragma unroll
        for (int j = 0; j < 4; ++j)
          acc[i][j] = fmaf(a[i], bb[j], acc[i][j]);
    }
  }
  const float inv = rsqrtf(1.f + 1e-5f);
  #pragma unroll
  for (int i = 0; i < 4; ++i) {
    int m = m0 + ty * 4 + i;
    if (m >= M) continue;
    #pragma unroll
    for (int j = 0; j < 4; ++j) {
      int n = n0 + tx * 4 + j;
      if (n >= N) continue;
      float v = acc[i][j];
      if (EPI == 1) {
        v = fmaxf(fmaf(v, sc[n] * inv, bi[n]), 0.f);
      } else if (EPI == 2) {
        float x = v + bi[n];
        v = (x > 20.f) ? x : log1pf(__expf(x));
      } else if (EPI == 3) {
        v = sigmoidf_(v + bi[n]);
      }
      C[(size_t)m * N + n] = v;
    }
  }
}

// ---------------- LayerNorm over 768 features (safe in-place) --------------
__global__ __launch_bounds__(256)
void layernorm768(const float* __restrict__ in, const float* __restrict__ g,
                  const float* __restrict__ b, float* __restrict__ out)
{
  const int row = blockIdx.x;
  const float* x = in + (size_t)row * 768;
  const int tid = threadIdx.x;
  float v0 = x[tid], v1 = x[tid + 256], v2 = x[tid + 512];
  float s = v0 + v1 + v2;
  float q = v0 * v0 + v1 * v1 + v2 * v2;
  #pragma unroll
  for (int off = 32; off >= 1; off >>= 1) {
    s += __shfl_down(s, off);
    q += __shfl_down(q, off);
  }
  __shared__ float rs[4], rq[4];
  int wave = tid >> 6;
  if ((tid & 63) == 0) { rs[wave] = s; rq[wave] = q; }
  __syncthreads();
  float ts = rs[0] + rs[1] + rs[2] + rs[3];
  float tq = rq[0] + rq[1] + rq[2] + rq[3];
  float mu = ts * (1.f / 768.f);
  float var = tq * (1.f / 768.f) - mu * mu;
  float rstd = rsqrtf(var + 1e-5f);
  float* o = out + (size_t)row * 768;
  o[tid]       = (v0 - mu) * rstd * g[tid]       + b[tid];
  o[tid + 256] = (v1 - mu) * rstd * g[tid + 256] + b[tid + 256];
  o[tid + 512] = (v2 - mu) * rstd * g[tid + 512] + b[tid + 512];
}

// ---------------- depthwise causal conv (K=4) + SiLU -----------------------
__global__ __launch_bounds__(256)
void dwconv_silu(const float* __restrict__ xz, const float* __restrict__ cw,
                 const float* __restrict__ cb, float* __restrict__ xmc, int total)
{
  int idx = blockIdx.x * 256 + threadIdx.x;
  if (idx >= total) return;
  int d = idx % 1536;
  int t = (idx / 1536) % 1000;
  int b = idx / (1536 * 1000);
  float acc = cb[d];
  #pragma unroll
  for (int j = 0; j < 4; ++j) {
    int tt = t - 3 + j;
    if (tt >= 0)
      acc = fmaf(cw[d * 4 + j], xz[((size_t)(b * 1000 + tt)) * 3072 + d], acc);
  }
  xmc[idx] = acc * sigmoidf_(acc);
}

// ---------------- selective scan + D skip + SiLU(z) gate -------------------
// g_out may alias dt (element [r,d] read before written by its sole owner).
__global__ __launch_bounds__(64)
void scan_kernel(const float* __restrict__ dt, const float* __restrict__ xmc,
                 const float* __restrict__ dbl, const float* __restrict__ xz,
                 const float* __restrict__ A_log, const float* __restrict__ Dp,
                 float* __restrict__ g_out)
{
  const int d = blockIdx.x * 64 + threadIdx.x;
  const int b = blockIdx.y;
  float A[16], h[16];
  #pragma unroll
  for (int n = 0; n < 16; ++n) {
    A[n] = -__expf(A_log[d * 16 + n]);
    h[n] = 0.f;
  }
  const float Dd = Dp[d];
  for (int t = 0; t < 1000; ++t) {
    size_t r = (size_t)b * 1000 + t;
    float dtv = dt[r * 1536 + d];
    float xv  = xmc[r * 1536 + d];
    float zv  = xz[r * 3072 + 1536 + d];
    const float* bc = dbl + r * 80;
    float dtx = dtv * xv;
    float y = 0.f;
    #pragma unroll
    for (int n = 0; n < 16; ++n) {
      float dA = __expf(dtv * A[n]);
      float hn = fmaf(dA, h[n], dtx * bc[48 + n]);
      h[n] = hn;
      y = fmaf(hn, bc[64 + n], y);
    }
    y = fmaf(xv, Dd, y);
    g_out[r * 1536 + d] = y * (zv * sigmoidf_(zv));
  }
}

// ---------------------------------------------------------------------------
extern "C" void kernel_launch(void* const* d_in, const int* in_sizes, int n_in,
                              void* d_out, int out_size, void* d_ws, size_t ws_size,
                              hipStream_t stream)
{
  const float* x    = (const float*)d_in[0];
  const float* cw1[4] = {(const float*)d_in[1],  (const float*)d_in[7],
                         (const float*)d_in[13], (const float*)d_in[19]};
  const float* cg1[4] = {(const float*)d_in[2],  (const float*)d_in[8],
                         (const float*)d_in[14], (const float*)d_in[20]};
  const float* cb1[4] = {(const float*)d_in[3],  (const float*)d_in[9],
                         (const float*)d_in[15], (const float*)d_in[21]};
  const float* cw2[4] = {(const float*)d_in[4],  (const float*)d_in[10],
                         (const float*)d_in[16], (const float*)d_in[22]};
  const float* cg2[4] = {(const float*)d_in[5],  (const float*)d_in[11],
                         (const float*)d_in[17], (const float*)d_in[23]};
  const float* cb2[4] = {(const float*)d_in[6],  (const float*)d_in[12],
                         (const float*)d_in[18], (const float*)d_in[24]};
  const float* fc5w = (const float*)d_in[25]; const float* bn5g = (const float*)d_in[26]; const float* bn5b = (const float*)d_in[27];
  const float* lng  = (const float*)d_in[28]; const float* lnb  = (const float*)d_in[29];
  const float* minw = (const float*)d_in[30]; const float* mcw  = (const float*)d_in[31]; const float* mcb  = (const float*)d_in[32];
  const float* mxw  = (const float*)d_in[33]; const float* mdtw = (const float*)d_in[34]; const float* mdtb = (const float*)d_in[35];
  const float* malog= (const float*)d_in[36]; const float* mD   = (const float*)d_in[37]; const float* moutw= (const float*)d_in[38];
  const float* pw   = (const float*)d_in[39]; const float* pb   = (const float*)d_in[40];

  char* ws = (char*)d_ws;
  // conv phase (per-b):      [0, 46M) convA | [46M, 70M) convB | [70M, ~98.7M) feat
  float* convA = (float*)(ws + 0);
  float* convB = (float*)(ws + 46000000);
  float* feat  = (float*)(ws + 70000000);          // [4000][1792]
  // post-conv phase (conv regions dead; feat dead after fc5):
  float* hfc  = (float*)(ws + 0);                  // [4000][768], LN in-place
  float* xzb  = (float*)(ws + 13000000);           // [4000][3072]
  float* xmc  = (float*)(ws + 63000000);           // [4000][1536]
  float* dblb = (float*)(ws + 88000000);           // [4000][80]
  float* dtb  = (float*)(ws + 90000000);           // [4000][1536]; scan writes in-place
  float* mam  = (float*)(ws + 115000000);          // [4000][768]

  dim3 blk(256);

  for (int b = 0; b < 4; ++b) {
    const float* xb = x + (size_t)b * 1000 * 229;
    float* featb = feat + (size_t)b * 1000 * 1792;
    // block 1
    conv3x3_bn_relu<1, 48, 229, 1, 64, 4>
        <<<dim3(3, 1000), blk, 0, stream>>>(xb, cw1[0], cg1[0], cb1[0], convA);
    conv3x3_pool_bn_relu<48, 48, 229, 8, 32, 6, false>
        <<<dim3(1, 1000), blk, 0, stream>>>(convA, cw2[0], cg2[0], cb2[0], convB);
    // block 2
    conv3x3_bn_relu<48, 64, 114, 8, 32, 8>
        <<<dim3(1, 1000), blk, 0, stream>>>(convB, cw1[1], cg1[1], cb1[1], convA);
    conv3x3_pool_bn_relu<64, 64, 114, 8, 16, 4, false>
        <<<dim3(1, 1000), blk, 0, stream>>>(convA, cw2[1], cg2[1], cb2[1], convB);
    // block 3
    conv3x3_bn_relu<64, 96, 57, 8, 16, 6>
        <<<dim3(1, 1000), blk, 0, stream>>>(convB, cw1[2], cg1[2], cb1[2], convA);
    conv3x3_pool_bn_relu<96, 96, 57, 8, 8, 3, false>
        <<<dim3(1, 1000), blk, 0, stream>>>(convA, cw2[2], cg2[2], cb2[2], convB);
    // block 4
    conv3x3_bn_relu<96, 128, 28, 8, 8, 4>
        <<<dim3(1, 1000), blk, 0, stream>>>(convB, cw1[3], cg1[3], cb1[3], convA);
    conv3x3_pool_bn_relu<128, 128, 28, 8, 8, 4, true>
        <<<dim3(1, 1000), blk, 0, stream>>>(convA, cw2[3], cg2[3], cb2[3], featb);
  }

  // ---- fc5 + BN + ReLU ----
  gemm_nt<1><<<dim3(12, 63), blk, 0, stream>>>(feat, 1792, fc5w, hfc, 4000, 768, 1792, bn5g, bn5b);
  // ---- LayerNorm (in-place) ----
  layernorm768<<<dim3(4000), blk, 0, stream>>>(hfc, lng, lnb, hfc);
  // ---- mamba in_proj ----
  gemm_nt<0><<<dim3(48, 63), blk, 0, stream>>>(hfc, 768, minw, xzb, 4000, 3072, 768, nullptr, nullptr);
  // ---- depthwise causal conv + silu ----
  dwconv_silu<<<dim3((6144000 + 255) / 256), blk, 0, stream>>>(xzb, mcw, mcb, xmc, 6144000);
  // ---- x_proj ----
  gemm_nt<0><<<dim3(2, 63), blk, 0, stream>>>(xmc, 1536, mxw, dblb, 4000, 80, 1536, nullptr, nullptr);
  // ---- dt = softplus(dbl[:, :48] @ dt_w^T + dt_b) ----
  gemm_nt<2><<<dim3(24, 63), blk, 0, stream>>>(dblb, 80, mdtw, dtb, 4000, 1536, 48, nullptr, mdtb);
  // ---- selective scan + D skip + gate (writes dtb in place) ----
  scan_kernel<<<dim3(24, 4), dim3(64), 0, stream>>>(dtb, xmc, dblb, xzb, malog, mD, dtb);
  // ---- out_proj ----
  gemm_nt<0><<<dim3(12, 63), blk, 0, stream>>>(dtb, 1536, moutw, mam, 4000, 768, 1536, nullptr, nullptr);
  // ---- final proj + sigmoid -> d_out ----
  gemm_nt<3><<<dim3(2, 63), blk, 0, stream>>>(mam, 768, pw, (float*)d_out, 4000, 88, 768, nullptr, pb);
}

// Round 7
// 2913.973 us; speedup vs baseline: 3.1045x; 3.1045x over previous
//
#include <hip/hip_runtime.h>
#include <math.h>

// ---------------------------------------------------------------------------
// Round 7: conv stack -> bf16 MFMA shift-GEMM (channel-last, zero-padded
// [T+2][F+2][Cp] activations; conv3x3 = sum of 9 shifted GEMMs, K = 9*Cp_in).
// Everything after the conv stack (fp32 GEMMs, LN, dwconv, scan) is identical
// to the round-6 passing baseline.
// ---------------------------------------------------------------------------

static __device__ __forceinline__ float sigmoidf_(float x) {
  return 1.f / (1.f + __expf(-x));
}
static __device__ __forceinline__ unsigned short f2bf(float f) {
  union { float f; unsigned int u; } c; c.f = f;
  unsigned int u = c.u;
  unsigned int r = (u + 0x7FFFu + ((u >> 16) & 1u)) >> 16;   // RTNE
  return (unsigned short)r;
}
static __device__ __forceinline__ float bf2f(unsigned short b) {
  union { unsigned int u; float f; } c; c.u = ((unsigned int)b) << 16;
  return c.f;
}

typedef __attribute__((ext_vector_type(8))) short short8b;
typedef __attribute__((ext_vector_type(4))) float f32x4;
typedef __attribute__((ext_vector_type(4))) unsigned short ushort4b;

// ---------------- zero the padded borders of an act buffer -----------------
__global__ __launch_bounds__(256)
void zero_border(unsigned short* __restrict__ buf, int F, int Cp, int total)
{
  int idx = blockIdx.x * 256 + threadIdx.x;
  if (idx >= total) return;
  int rowelems = (F + 2) * Cp;
  if (idx < 2 * rowelems) {
    int r = idx / rowelems;            // 0 -> t=0, 1 -> t=1001
    int k = idx % rowelems;
    buf[(size_t)(r * 1001) * rowelems + k] = 0;
  } else {
    int j = idx - 2 * rowelems;
    int t = j / (2 * Cp) + 1;
    int side = (j / Cp) & 1;
    int c = j % Cp;
    buf[((size_t)t * (F + 2) + (side ? F + 1 : 0)) * Cp + c] = 0;
  }
}

// ---------------- weight transform: [CO][CIN][3][3] f32 -> [9][COp][Cpin] bf16
__global__ __launch_bounds__(256)
void wt_transform(const float* __restrict__ W, unsigned short* __restrict__ dst,
                  int CO, int CIN, int COp, int Cpin, int total)
{
  int idx = blockIdx.x * 256 + threadIdx.x;
  if (idx >= total) return;
  int ci = idx % Cpin;
  int co = (idx / Cpin) % COp;
  int s  = idx / (Cpin * COp);
  float v = (co < CO && ci < CIN) ? W[((size_t)co * CIN + ci) * 9 + s] : 0.f;
  dst[idx] = f2bf(v);
}

// ---------------- first conv (CIN=1) fp32 -> padded bf16 -------------------
// x [1000][229] (one batch), W [48][9], out [1002][231][64].
__global__ __launch_bounds__(256)
void conv1_first(const float* __restrict__ x, const float* __restrict__ W,
                 const float* __restrict__ g, const float* __restrict__ bt,
                 unsigned short* __restrict__ out)
{
  __shared__ float ws[48 * 9];
  __shared__ float xs[3][6];
  const int tid = threadIdx.x;
  const int f0 = blockIdx.x * 4;
  const int t  = blockIdx.y;
  for (int i = tid; i < 48 * 9; i += 256) ws[i] = W[i];
  if (tid < 18) {
    int r = tid / 6, c = tid % 6;
    int ff = f0 - 1 + c, tt = t - 1 + r;
    xs[r][c] = (ff >= 0 && ff < 229 && tt >= 0 && tt < 1000)
                   ? x[tt * 229 + ff] : 0.f;
  }
  __syncthreads();
  const int co = tid & 63;
  const int fi = tid >> 6;
  const int f  = f0 + fi;
  float v = 0.f;
  if (co < 48) {
    float acc = 0.f;
    #pragma unroll
    for (int ky = 0; ky < 3; ++ky)
      #pragma unroll
      for (int kx = 0; kx < 3; ++kx)
        acc = fmaf(ws[co * 9 + ky * 3 + kx], xs[ky][fi + kx], acc);
    const float inv = rsqrtf(1.f + 1e-5f);
    v = fmaxf(fmaf(acc, g[co] * inv, bt[co]), 0.f);
  }
  if (f < 229)
    out[((size_t)(t + 1) * 231 + f + 1) * 64 + co] = f2bf(v);
}

// ---------------- MFMA shift-GEMM conv3x3 + BN + ReLU ----------------------
// act in [1002][F+2][Cpin] bf16 (borders zero), W9 [9][COp][Cpin] bf16,
// out [1002][F+2][COp] bf16 (interior only). M = 1000*F positions.
template<int COp, int Cpin, int F, int BM, int CO>
__global__ __launch_bounds__(256)
void conv_mfma(const unsigned short* __restrict__ act,
               const unsigned short* __restrict__ W9,
               const float* __restrict__ gam, const float* __restrict__ bet,
               unsigned short* __restrict__ out, int M)
{
  static_assert(BM == 64 || BM == 128, "");
  constexpr int MI = BM / 32;        // M frags per wave (wave M = BM/2)
  constexpr int NJ = COp / 32;       // N frags per wave (wave N = COp/2)
  constexpr int KSTEPS = Cpin / 32;
  __shared__ alignas(16) short A_s[4 * BM * 8];    // [q][row][8] q-major
  __shared__ alignas(16) short B_s[4 * COp * 8];   // [q][co][8]

  const int tid  = threadIdx.x;
  const int lane = tid & 63, w = tid >> 6;
  const int wm = w >> 1, wn = w & 1;
  const int m0 = blockIdx.x * BM;

  // Precompute padded-row addrs for this thread's A slots (q-major slot = tid..)
  int prA[BM / 64];
  #pragma unroll
  for (int j = 0; j < BM / 64; ++j) {
    int slot = j * 256 + tid;
    int row  = slot % BM;
    int pos  = m0 + row; if (pos >= M) pos = M - 1;
    int t = pos / F, f = pos - t * F;
    prA[j] = (t + 1) * (F + 2) + (f + 1);
  }

  f32x4 acc[MI][NJ];
  #pragma unroll
  for (int i = 0; i < MI; ++i)
    #pragma unroll
    for (int jn = 0; jn < NJ; ++jn) acc[i][jn] = (f32x4){0.f, 0.f, 0.f, 0.f};

  for (int s = 0; s < 9; ++s) {
    const int soff = (s / 3 - 1) * (F + 2) + (s % 3) - 1;
    for (int kc = 0; kc < KSTEPS; ++kc) {
      __syncthreads();
      // stage A (slot = q*BM+row; LDS write linear in slot -> conflict-free)
      #pragma unroll
      for (int j = 0; j < BM / 64; ++j) {
        int slot = j * 256 + tid;
        int q = slot / BM;
        short8b v = *(const short8b*)
            &act[(size_t)(prA[j] + soff) * Cpin + kc * 32 + q * 8];
        *(short8b*)&A_s[slot * 8] = v;
      }
      // stage B
      #pragma unroll
      for (int sb = 0; sb < (COp * 4 + 255) / 256; ++sb) {
        int slot = sb * 256 + tid;
        if (slot < COp * 4) {
          int q = slot / COp, co = slot % COp;
          short8b v = *(const short8b*)
              &W9[((size_t)(s * COp + co)) * Cpin + kc * 32 + q * 8];
          *(short8b*)&B_s[slot * 8] = v;
        }
      }
      __syncthreads();
      // fragments + MFMA
      const int lr = lane & 15, lq = lane >> 4;
      short8b a[MI], b[NJ];
      #pragma unroll
      for (int i = 0; i < MI; ++i)
        a[i] = *(const short8b*)&A_s[(lq * BM + wm * (BM / 2) + i * 16 + lr) * 8];
      #pragma unroll
      for (int jn = 0; jn < NJ; ++jn)
        b[jn] = *(const short8b*)&B_s[(lq * COp + wn * (COp / 2) + jn * 16 + lr) * 8];
      #pragma unroll
      for (int i = 0; i < MI; ++i)
        #pragma unroll
        for (int jn = 0; jn < NJ; ++jn)
          acc[i][jn] = __builtin_amdgcn_mfma_f32_16x16x32_bf16(
              a[i], b[jn], acc[i][jn], 0, 0, 0);
    }
  }
  // epilogue: C row = pos (m), col = co (n); m89 mapping col=lane&15,
  // row=(lane>>4)*4+reg.
  const float inv = rsqrtf(1.f + 1e-5f);
  const int lr = lane & 15, lq = lane >> 4;
  #pragma unroll
  for (int jn = 0; jn < NJ; ++jn) {
    int co = wn * (COp / 2) + jn * 16 + lr;
    float sc = (co < CO) ? gam[co] * inv : 0.f;
    float bi = (co < CO) ? bet[co] : 0.f;
    #pragma unroll
    for (int i = 0; i < MI; ++i) {
      #pragma unroll
      for (int r = 0; r < 4; ++r) {
        int pos = m0 + wm * (BM / 2) + i * 16 + lq * 4 + r;
        if (pos < M) {
          int t = pos / F, f = pos - t * F;
          float v = fmaxf(fmaf(acc[i][jn][r], sc, bi), 0.f);
          out[((size_t)(t + 1) * (F + 2) + f + 1) * COp + co] = f2bf(v);
        }
      }
    }
  }
}

// ---------------- avg-pool /2 along F, padded bf16 -> padded bf16 ----------
__global__ __launch_bounds__(256)
void pool_ch(const unsigned short* __restrict__ in, unsigned short* __restrict__ out,
             int Fin, int Fo, int Cp, int total4)
{
  int idx = blockIdx.x * 256 + threadIdx.x;
  if (idx >= total4) return;
  int cg = Cp / 4;
  int c4 = idx % cg;
  int fo = (idx / cg) % Fo;
  int t  = idx / (cg * Fo);
  size_t bi = ((size_t)(t + 1) * (Fin + 2) + 2 * fo + 1) * Cp + c4 * 4;
  ushort4b a = *(const ushort4b*)&in[bi];
  ushort4b b = *(const ushort4b*)&in[bi + Cp];
  ushort4b o;
  #pragma unroll
  for (int e = 0; e < 4; ++e)
    o[e] = f2bf((bf2f(a[e]) + bf2f(b[e])) * 0.5f);
  *(ushort4b*)&out[((size_t)(t + 1) * (Fo + 2) + fo + 1) * Cp + c4 * 4] = o;
}

// ---------------- final pool -> transposed fp32 features -------------------
// in [1002][30][128] bf16 -> feat[(boff+t)*1792 + co*14 + fo] fp32.
__global__ __launch_bounds__(256)
void pool4_trans(const unsigned short* __restrict__ in, float* __restrict__ feat,
                 int boff)
{
  int idx = blockIdx.x * 256 + threadIdx.x;
  if (idx >= 1000 * 128 * 14) return;
  int fo = idx % 14;
  int co = (idx / 14) % 128;
  int t  = idx / (14 * 128);
  size_t bi = ((size_t)(t + 1) * 30 + 2 * fo + 1) * 128 + co;
  float v = (bf2f(in[bi]) + bf2f(in[bi + 128])) * 0.5f;
  feat[((size_t)(boff + t)) * 1792 + co * 14 + fo] = v;
}

// ---------------- generic tiled fp32 GEMM: C[M,N] = A[M,K] * W[N,K]^T ------
// EPI: 0 none; 1 relu(v*sc[n]/sqrt(1+eps)+bi[n]); 2 softplus(v+bi[n]);
//      3 sigmoid(v+bi[n]).   Requires K % 16 == 0.
template<int EPI>
__global__ __launch_bounds__(256)
void gemm_nt(const float* __restrict__ A, int lda,
             const float* __restrict__ W,
             float* __restrict__ C, int M, int N, int K,
             const float* __restrict__ sc, const float* __restrict__ bi)
{
  __shared__ float As[16][68];
  __shared__ float Bs[16][68];
  const int tid = threadIdx.x;
  const int m0 = blockIdx.y * 64, n0 = blockIdx.x * 64;
  const int tx = tid % 16, ty = tid / 16;
  const int lr = tid / 4, lk = (tid % 4) * 4;
  float acc[4][4];
  #pragma unroll
  for (int i = 0; i < 4; ++i)
    #pragma unroll
    for (int j = 0; j < 4; ++j) acc[i][j] = 0.f;

  for (int k0 = 0; k0 < K; k0 += 16) {
    __syncthreads();
    {
      int m = m0 + lr;
      float4 a = make_float4(0.f, 0.f, 0.f, 0.f);
      if (m < M) a = *(const float4*)(A + (size_t)m * lda + k0 + lk);
      As[lk + 0][lr] = a.x; As[lk + 1][lr] = a.y;
      As[lk + 2][lr] = a.z; As[lk + 3][lr] = a.w;
      int n = n0 + lr;
      float4 wv = make_float4(0.f, 0.f, 0.f, 0.f);
      if (n < N) wv = *(const float4*)(W + (size_t)n * K + k0 + lk);
      Bs[lk + 0][lr] = wv.x; Bs[lk + 1][lr] = wv.y;
      Bs[lk + 2][lr] = wv.z; Bs[lk + 3][lr] = wv.w;
    }
    __syncthreads();
    #pragma unroll
    for (int kk = 0; kk < 16; ++kk) {
      float4 av = *(const float4*)(&As[kk][ty * 4]);
      float4 bv = *(const float4*)(&Bs[kk][tx * 4]);
      float a[4] = {av.x, av.y, av.z, av.w};
      float bb[4] = {bv.x, bv.y, bv.z, bv.w};
      #pragma unroll
      for (int i = 0; i < 4; ++i)
        #pragma unroll
        for (int j = 0; j < 4; ++j)
          acc[i][j] = fmaf(a[i], bb[j], acc[i][j]);
    }
  }
  const float inv = rsqrtf(1.f + 1e-5f);
  #pragma unroll
  for (int i = 0; i < 4; ++i) {
    int m = m0 + ty * 4 + i;
    if (m >= M) continue;
    #pragma unroll
    for (int j = 0; j < 4; ++j) {
      int n = n0 + tx * 4 + j;
      if (n >= N) continue;
      float v = acc[i][j];
      if (EPI == 1) {
        v = fmaxf(fmaf(v, sc[n] * inv, bi[n]), 0.f);
      } else if (EPI == 2) {
        float x = v + bi[n];
        v = (x > 20.f) ? x : log1pf(__expf(x));
      } else if (EPI == 3) {
        v = sigmoidf_(v + bi[n]);
      }
      C[(size_t)m * N + n] = v;
    }
  }
}

// ---------------- LayerNorm over 768 features (safe in-place) --------------
__global__ __launch_bounds__(256)
void layernorm768(const float* __restrict__ in, const float* __restrict__ g,
                  const float* __restrict__ b, float* __restrict__ out)
{
  const int row = blockIdx.x;
  const float* x = in + (size_t)row * 768;
  const int tid = threadIdx.x;
  float v0 = x[tid], v1 = x[tid + 256], v2 = x[tid + 512];
  float s = v0 + v1 + v2;
  float q = v0 * v0 + v1 * v1 + v2 * v2;
  #pragma unroll
  for (int off = 32; off >= 1; off >>= 1) {
    s += __shfl_down(s, off);
    q += __shfl_down(q, off);
  }
  __shared__ float rs[4], rq[4];
  int wave = tid >> 6;
  if ((tid & 63) == 0) { rs[wave] = s; rq[wave] = q; }
  __syncthreads();
  float ts = rs[0] + rs[1] + rs[2] + rs[3];
  float tq = rq[0] + rq[1] + rq[2] + rq[3];
  float mu = ts * (1.f / 768.f);
  float var = tq * (1.f / 768.f) - mu * mu;
  float rstd = rsqrtf(var + 1e-5f);
  float* o = out + (size_t)row * 768;
  o[tid]       = (v0 - mu) * rstd * g[tid]       + b[tid];
  o[tid + 256] = (v1 - mu) * rstd * g[tid + 256] + b[tid + 256];
  o[tid + 512] = (v2 - mu) * rstd * g[tid + 512] + b[tid + 512];
}

// ---------------- depthwise causal conv (K=4) + SiLU -----------------------
__global__ __launch_bounds__(256)
void dwconv_silu(const float* __restrict__ xz, const float* __restrict__ cw,
                 const float* __restrict__ cb, float* __restrict__ xmc, int total)
{
  int idx = blockIdx.x * 256 + threadIdx.x;
  if (idx >= total) return;
  int d = idx % 1536;
  int t = (idx / 1536) % 1000;
  int b = idx / (1536 * 1000);
  float acc = cb[d];
  #pragma unroll
  for (int j = 0; j < 4; ++j) {
    int tt = t - 3 + j;
    if (tt >= 0)
      acc = fmaf(cw[d * 4 + j], xz[((size_t)(b * 1000 + tt)) * 3072 + d], acc);
  }
  xmc[idx] = acc * sigmoidf_(acc);
}

// ---------------- selective scan + D skip + SiLU(z) gate -------------------
__global__ __launch_bounds__(64)
void scan_kernel(const float* __restrict__ dt, const float* __restrict__ xmc,
                 const float* __restrict__ dbl, const float* __restrict__ xz,
                 const float* __restrict__ A_log, const float* __restrict__ Dp,
                 float* __restrict__ g_out)
{
  const int d = blockIdx.x * 64 + threadIdx.x;
  const int b = blockIdx.y;
  float A[16], h[16];
  #pragma unroll
  for (int n = 0; n < 16; ++n) {
    A[n] = -__expf(A_log[d * 16 + n]);
    h[n] = 0.f;
  }
  const float Dd = Dp[d];
  for (int t = 0; t < 1000; ++t) {
    size_t r = (size_t)b * 1000 + t;
    float dtv = dt[r * 1536 + d];
    float xv  = xmc[r * 1536 + d];
    float zv  = xz[r * 3072 + 1536 + d];
    const float* bc = dbl + r * 80;
    float dtx = dtv * xv;
    float y = 0.f;
    #pragma unroll
    for (int n = 0; n < 16; ++n) {
      float dA = __expf(dtv * A[n]);
      float hn = fmaf(dA, h[n], dtx * bc[48 + n]);
      h[n] = hn;
      y = fmaf(hn, bc[64 + n], y);
    }
    y = fmaf(xv, Dd, y);
    g_out[r * 1536 + d] = y * (zv * sigmoidf_(zv));
  }
}

// ---------------------------------------------------------------------------
extern "C" void kernel_launch(void* const* d_in, const int* in_sizes, int n_in,
                              void* d_out, int out_size, void* d_ws, size_t ws_size,
                              hipStream_t stream)
{
  const float* x    = (const float*)d_in[0];
  const float* cw1[4] = {(const float*)d_in[1],  (const float*)d_in[7],
                         (const float*)d_in[13], (const float*)d_in[19]};
  const float* cg1[4] = {(const float*)d_in[2],  (const float*)d_in[8],
                         (const float*)d_in[14], (const float*)d_in[20]};
  const float* cb1[4] = {(const float*)d_in[3],  (const float*)d_in[9],
                         (const float*)d_in[15], (const float*)d_in[21]};
  const float* cw2[4] = {(const float*)d_in[4],  (const float*)d_in[10],
                         (const float*)d_in[16], (const float*)d_in[22]};
  const float* cg2[4] = {(const float*)d_in[5],  (const float*)d_in[11],
                         (const float*)d_in[17], (const float*)d_in[23]};
  const float* cb2[4] = {(const float*)d_in[6],  (const float*)d_in[12],
                         (const float*)d_in[18], (const float*)d_in[24]};
  const float* fc5w = (const float*)d_in[25]; const float* bn5g = (const float*)d_in[26]; const float* bn5b = (const float*)d_in[27];
  const float* lng  = (const float*)d_in[28]; const float* lnb  = (const float*)d_in[29];
  const float* minw = (const float*)d_in[30]; const float* mcw  = (const float*)d_in[31]; const float* mcb  = (const float*)d_in[32];
  const float* mxw  = (const float*)d_in[33]; const float* mdtw = (const float*)d_in[34]; const float* mdtb = (const float*)d_in[35];
  const float* malog= (const float*)d_in[36]; const float* mD   = (const float*)d_in[37]; const float* moutw= (const float*)d_in[38];
  const float* pw   = (const float*)d_in[39]; const float* pb   = (const float*)d_in[40];

  char* ws = (char*)d_ws;
  // conv phase:
  unsigned short* bufA = (unsigned short*)(ws + 0);           // 30 MB
  unsigned short* bufB = (unsigned short*)(ws + 30000000);    // 30 MB
  unsigned short* w1b = (unsigned short*)(ws + 60000000);
  unsigned short* w2a = (unsigned short*)(ws + 60100000);
  unsigned short* w2b = (unsigned short*)(ws + 60200000);
  unsigned short* w3a = (unsigned short*)(ws + 60300000);
  unsigned short* w3b = (unsigned short*)(ws + 60450000);
  unsigned short* w4a = (unsigned short*)(ws + 60650000);
  unsigned short* w4b = (unsigned short*)(ws + 60900000);
  float* feat = (float*)(ws + 61500000);                      // [4000][1792]
  float* hfc  = (float*)(ws + 90200000);                      // [4000][768]
  // post-conv phase (conv bufs + W9 + feat become dead in this order):
  float* xzb  = (float*)(ws + 0);                             // [4000][3072]
  float* xmc  = (float*)(ws + 49200000);                      // [4000][1536]
  float* dblb = (float*)(ws + 74000000);                      // [4000][80]
  float* mam  = (float*)(ws + 75500000);                      // [4000][768]
  float* dtb  = (float*)(ws + 102500000);                     // [4000][1536]

  dim3 blk(256);

  // ---- weight transforms (once) ----
  {
    struct WT { const float* src; unsigned short* dst; int CO, CIN, COp, Cpin; };
    WT wt[7] = {
      {cw2[0], w1b,  48,  48,  64,  64},
      {cw1[1], w2a,  64,  48,  64,  64},
      {cw2[1], w2b,  64,  64,  64,  64},
      {cw1[2], w3a,  96,  64,  96,  64},
      {cw2[2], w3b,  96,  96,  96,  96},
      {cw1[3], w4a, 128,  96, 128,  96},
      {cw2[3], w4b, 128, 128, 128, 128},
    };
    for (int i = 0; i < 7; ++i) {
      int total = 9 * wt[i].COp * wt[i].Cpin;
      wt_transform<<<dim3((total + 255) / 256), blk, 0, stream>>>(
          wt[i].src, wt[i].dst, wt[i].CO, wt[i].CIN, wt[i].COp, wt[i].Cpin, total);
    }
  }

  auto zb = [&](unsigned short* buf, int F, int Cp) {
    int total = 2 * (F + 2) * Cp + 2000 * Cp;
    zero_border<<<dim3((total + 255) / 256), blk, 0, stream>>>(buf, F, Cp, total);
  };
  auto pool = [&](const unsigned short* in, unsigned short* out,
                  int Fin, int Fo, int Cp) {
    int total4 = 1000 * Fo * Cp / 4;
    pool_ch<<<dim3((total4 + 255) / 256), blk, 0, stream>>>(in, out, Fin, Fo, Cp, total4);
  };

  for (int b = 0; b < 4; ++b) {
    const float* xb = x + (size_t)b * 1000 * 229;
    // L1a: CIN=1 fp32 -> bufA [1002][231][64]
    zb(bufA, 229, 64);
    conv1_first<<<dim3(58, 1000), blk, 0, stream>>>(xb, cw1[0], cg1[0], cb1[0], bufA);
    // L1b: 48->48 (pad 64), F=229 -> bufB
    zb(bufB, 229, 64);
    conv_mfma<64, 64, 229, 128, 48><<<dim3(1790), blk, 0, stream>>>(
        bufA, w1b, cg2[0], cb2[0], bufB, 229000);
    // pool1 -> bufA [1002][116][64]
    zb(bufA, 114, 64);
    pool(bufB, bufA, 229, 114, 64);
    // L2a: 48->64, F=114 -> bufB
    zb(bufB, 114, 64);
    conv_mfma<64, 64, 114, 128, 64><<<dim3(891), blk, 0, stream>>>(
        bufA, w2a, cg1[1], cb1[1], bufB, 114000);
    // L2b: 64->64 -> bufA
    zb(bufA, 114, 64);
    conv_mfma<64, 64, 114, 128, 64><<<dim3(891), blk, 0, stream>>>(
        bufB, w2b, cg2[1], cb2[1], bufA, 114000);
    // pool2 -> bufB [1002][59][64]
    zb(bufB, 57, 64);
    pool(bufA, bufB, 114, 57, 64);
    // L3a: 64->96, F=57 -> bufA
    zb(bufA, 57, 96);
    conv_mfma<96, 64, 57, 128, 96><<<dim3(446), blk, 0, stream>>>(
        bufB, w3a, cg1[2], cb1[2], bufA, 57000);
    // L3b: 96->96 -> bufB
    zb(bufB, 57, 96);
    conv_mfma<96, 96, 57, 128, 96><<<dim3(446), blk, 0, stream>>>(
        bufA, w3b, cg2[2], cb2[2], bufB, 57000);
    // pool3 -> bufA [1002][30][96]
    zb(bufA, 28, 96);
    pool(bufB, bufA, 57, 28, 96);
    // L4a: 96->128, F=28 -> bufB
    zb(bufB, 28, 128);
    conv_mfma<128, 96, 28, 64, 128><<<dim3(438), blk, 0, stream>>>(
        bufA, w4a, cg1[3], cb1[3], bufB, 28000);
    // L4b: 128->128 -> bufA
    zb(bufA, 28, 128);
    conv_mfma<128, 128, 28, 64, 128><<<dim3(438), blk, 0, stream>>>(
        bufB, w4b, cg2[3], cb2[3], bufA, 28000);
    // pool4 + transpose -> feat
    pool4_trans<<<dim3((1000 * 128 * 14 + 255) / 256), blk, 0, stream>>>(
        bufA, feat, b * 1000);
  }

  // ---- fc5 + BN + ReLU ----
  gemm_nt<1><<<dim3(12, 63), blk, 0, stream>>>(feat, 1792, fc5w, hfc, 4000, 768, 1792, bn5g, bn5b);
  // ---- LayerNorm (in-place) ----
  layernorm768<<<dim3(4000), blk, 0, stream>>>(hfc, lng, lnb, hfc);
  // ---- mamba in_proj ----
  gemm_nt<0><<<dim3(48, 63), blk, 0, stream>>>(hfc, 768, minw, xzb, 4000, 3072, 768, nullptr, nullptr);
  // ---- depthwise causal conv + silu ----
  dwconv_silu<<<dim3((6144000 + 255) / 256), blk, 0, stream>>>(xzb, mcw, mcb, xmc, 6144000);
  // ---- x_proj ----
  gemm_nt<0><<<dim3(2, 63), blk, 0, stream>>>(xmc, 1536, mxw, dblb, 4000, 80, 1536, nullptr, nullptr);
  // ---- dt = softplus(dbl[:, :48] @ dt_w^T + dt_b) ----
  gemm_nt<2><<<dim3(24, 63), blk, 0, stream>>>(dblb, 80, mdtw, dtb, 4000, 1536, 48, nullptr, mdtb);
  // ---- selective scan + D skip + gate (writes dtb in place) ----
  scan_kernel<<<dim3(24, 4), dim3(64), 0, stream>>>(dtb, xmc, dblb, xzb, malog, mD, dtb);
  // ---- out_proj ----
  gemm_nt<0><<<dim3(12, 63), blk, 0, stream>>>(dtb, 1536, moutw, mam, 4000, 768, 1536, nullptr, nullptr);
  // ---- final proj + sigmoid -> d_out ----
  gemm_nt<3><<<dim3(2, 63), blk, 0, stream>>>(mam, 768, pw, (float*)d_out, 4000, 88, 768, nullptr, pb);
}

// Round 9
// 2282.375 us; speedup vs baseline: 3.9636x; 1.2767x over previous
//
#include <hip/hip_runtime.h>
#include <math.h>

// ---------------------------------------------------------------------------
// Round 9: resubmit of round-8 kernel (never ran — GPU acquisition timeout).
// (1) fc5/in_proj/out_proj -> MFMA bf16 GEMM with fp32->bf16 conversion in
// LDS staging; (2) selective scan -> 3-pass chunked parallel scan (10 chunks
// of 100 steps). Conv stack identical to round-7 (HW-verified).
// ---------------------------------------------------------------------------

static __device__ __forceinline__ float sigmoidf_(float x) {
  return 1.f / (1.f + __expf(-x));
}
static __device__ __forceinline__ unsigned short f2bf(float f) {
  union { float f; unsigned int u; } c; c.f = f;
  unsigned int u = c.u;
  unsigned int r = (u + 0x7FFFu + ((u >> 16) & 1u)) >> 16;   // RTNE
  return (unsigned short)r;
}
static __device__ __forceinline__ float bf2f(unsigned short b) {
  union { unsigned int u; float f; } c; c.u = ((unsigned int)b) << 16;
  return c.f;
}

typedef __attribute__((ext_vector_type(8))) short short8b;
typedef __attribute__((ext_vector_type(4))) float f32x4;
typedef __attribute__((ext_vector_type(4))) unsigned short ushort4b;

// ---------------- zero the padded borders of an act buffer -----------------
__global__ __launch_bounds__(256)
void zero_border(unsigned short* __restrict__ buf, int F, int Cp, int total)
{
  int idx = blockIdx.x * 256 + threadIdx.x;
  if (idx >= total) return;
  int rowelems = (F + 2) * Cp;
  if (idx < 2 * rowelems) {
    int r = idx / rowelems;
    int k = idx % rowelems;
    buf[(size_t)(r * 1001) * rowelems + k] = 0;
  } else {
    int j = idx - 2 * rowelems;
    int t = j / (2 * Cp) + 1;
    int side = (j / Cp) & 1;
    int c = j % Cp;
    buf[((size_t)t * (F + 2) + (side ? F + 1 : 0)) * Cp + c] = 0;
  }
}

// ---------------- weight transform: [CO][CIN][3][3] f32 -> [9][COp][Cpin] bf16
__global__ __launch_bounds__(256)
void wt_transform(const float* __restrict__ W, unsigned short* __restrict__ dst,
                  int CO, int CIN, int COp, int Cpin, int total)
{
  int idx = blockIdx.x * 256 + threadIdx.x;
  if (idx >= total) return;
  int ci = idx % Cpin;
  int co = (idx / Cpin) % COp;
  int s  = idx / (Cpin * COp);
  float v = (co < CO && ci < CIN) ? W[((size_t)co * CIN + ci) * 9 + s] : 0.f;
  dst[idx] = f2bf(v);
}

// ---------------- first conv (CIN=1) fp32 -> padded bf16 -------------------
__global__ __launch_bounds__(256)
void conv1_first(const float* __restrict__ x, const float* __restrict__ W,
                 const float* __restrict__ g, const float* __restrict__ bt,
                 unsigned short* __restrict__ out)
{
  __shared__ float ws[48 * 9];
  __shared__ float xs[3][6];
  const int tid = threadIdx.x;
  const int f0 = blockIdx.x * 4;
  const int t  = blockIdx.y;
  for (int i = tid; i < 48 * 9; i += 256) ws[i] = W[i];
  if (tid < 18) {
    int r = tid / 6, c = tid % 6;
    int ff = f0 - 1 + c, tt = t - 1 + r;
    xs[r][c] = (ff >= 0 && ff < 229 && tt >= 0 && tt < 1000)
                   ? x[tt * 229 + ff] : 0.f;
  }
  __syncthreads();
  const int co = tid & 63;
  const int fi = tid >> 6;
  const int f  = f0 + fi;
  float v = 0.f;
  if (co < 48) {
    float acc = 0.f;
    #pragma unroll
    for (int ky = 0; ky < 3; ++ky)
      #pragma unroll
      for (int kx = 0; kx < 3; ++kx)
        acc = fmaf(ws[co * 9 + ky * 3 + kx], xs[ky][fi + kx], acc);
    const float inv = rsqrtf(1.f + 1e-5f);
    v = fmaxf(fmaf(acc, g[co] * inv, bt[co]), 0.f);
  }
  if (f < 229)
    out[((size_t)(t + 1) * 231 + f + 1) * 64 + co] = f2bf(v);
}

// ---------------- MFMA shift-GEMM conv3x3 + BN + ReLU ----------------------
template<int COp, int Cpin, int F, int BM, int CO>
__global__ __launch_bounds__(256)
void conv_mfma(const unsigned short* __restrict__ act,
               const unsigned short* __restrict__ W9,
               const float* __restrict__ gam, const float* __restrict__ bet,
               unsigned short* __restrict__ out, int M)
{
  static_assert(BM == 64 || BM == 128, "");
  constexpr int MI = BM / 32;
  constexpr int NJ = COp / 32;
  constexpr int KSTEPS = Cpin / 32;
  __shared__ alignas(16) short A_s[4 * BM * 8];
  __shared__ alignas(16) short B_s[4 * COp * 8];

  const int tid  = threadIdx.x;
  const int lane = tid & 63, w = tid >> 6;
  const int wm = w >> 1, wn = w & 1;
  const int m0 = blockIdx.x * BM;

  int prA[BM / 64];
  #pragma unroll
  for (int j = 0; j < BM / 64; ++j) {
    int slot = j * 256 + tid;
    int row  = slot % BM;
    int pos  = m0 + row; if (pos >= M) pos = M - 1;
    int t = pos / F, f = pos - t * F;
    prA[j] = (t + 1) * (F + 2) + (f + 1);
  }

  f32x4 acc[MI][NJ];
  #pragma unroll
  for (int i = 0; i < MI; ++i)
    #pragma unroll
    for (int jn = 0; jn < NJ; ++jn) acc[i][jn] = (f32x4){0.f, 0.f, 0.f, 0.f};

  for (int s = 0; s < 9; ++s) {
    const int soff = (s / 3 - 1) * (F + 2) + (s % 3) - 1;
    for (int kc = 0; kc < KSTEPS; ++kc) {
      __syncthreads();
      #pragma unroll
      for (int j = 0; j < BM / 64; ++j) {
        int slot = j * 256 + tid;
        int q = slot / BM;
        short8b v = *(const short8b*)
            &act[(size_t)(prA[j] + soff) * Cpin + kc * 32 + q * 8];
        *(short8b*)&A_s[slot * 8] = v;
      }
      #pragma unroll
      for (int sb = 0; sb < (COp * 4 + 255) / 256; ++sb) {
        int slot = sb * 256 + tid;
        if (slot < COp * 4) {
          int q = slot / COp, co = slot % COp;
          short8b v = *(const short8b*)
              &W9[((size_t)(s * COp + co)) * Cpin + kc * 32 + q * 8];
          *(short8b*)&B_s[slot * 8] = v;
        }
      }
      __syncthreads();
      const int lr = lane & 15, lq = lane >> 4;
      short8b a[MI], b[NJ];
      #pragma unroll
      for (int i = 0; i < MI; ++i)
        a[i] = *(const short8b*)&A_s[(lq * BM + wm * (BM / 2) + i * 16 + lr) * 8];
      #pragma unroll
      for (int jn = 0; jn < NJ; ++jn)
        b[jn] = *(const short8b*)&B_s[(lq * COp + wn * (COp / 2) + jn * 16 + lr) * 8];
      #pragma unroll
      for (int i = 0; i < MI; ++i)
        #pragma unroll
        for (int jn = 0; jn < NJ; ++jn)
          acc[i][jn] = __builtin_amdgcn_mfma_f32_16x16x32_bf16(
              a[i], b[jn], acc[i][jn], 0, 0, 0);
    }
  }
  const float inv = rsqrtf(1.f + 1e-5f);
  const int lr = lane & 15, lq = lane >> 4;
  #pragma unroll
  for (int jn = 0; jn < NJ; ++jn) {
    int co = wn * (COp / 2) + jn * 16 + lr;
    float sc = (co < CO) ? gam[co] * inv : 0.f;
    float bi = (co < CO) ? bet[co] : 0.f;
    #pragma unroll
    for (int i = 0; i < MI; ++i) {
      #pragma unroll
      for (int r = 0; r < 4; ++r) {
        int pos = m0 + wm * (BM / 2) + i * 16 + lq * 4 + r;
        if (pos < M) {
          int t = pos / F, f = pos - t * F;
          float v = fmaxf(fmaf(acc[i][jn][r], sc, bi), 0.f);
          out[((size_t)(t + 1) * (F + 2) + f + 1) * COp + co] = f2bf(v);
        }
      }
    }
  }
}

// ---------------- avg-pool /2 along F, padded bf16 -> padded bf16 ----------
__global__ __launch_bounds__(256)
void pool_ch(const unsigned short* __restrict__ in, unsigned short* __restrict__ out,
             int Fin, int Fo, int Cp, int total4)
{
  int idx = blockIdx.x * 256 + threadIdx.x;
  if (idx >= total4) return;
  int cg = Cp / 4;
  int c4 = idx % cg;
  int fo = (idx / cg) % Fo;
  int t  = idx / (cg * Fo);
  size_t bi = ((size_t)(t + 1) * (Fin + 2) + 2 * fo + 1) * Cp + c4 * 4;
  ushort4b a = *(const ushort4b*)&in[bi];
  ushort4b b = *(const ushort4b*)&in[bi + Cp];
  ushort4b o;
  #pragma unroll
  for (int e = 0; e < 4; ++e)
    o[e] = f2bf((bf2f(a[e]) + bf2f(b[e])) * 0.5f);
  *(ushort4b*)&out[((size_t)(t + 1) * (Fo + 2) + fo + 1) * Cp + c4 * 4] = o;
}

// ---------------- final pool -> transposed fp32 features -------------------
__global__ __launch_bounds__(256)
void pool4_trans(const unsigned short* __restrict__ in, float* __restrict__ feat,
                 int boff)
{
  int idx = blockIdx.x * 256 + threadIdx.x;
  if (idx >= 1000 * 128 * 14) return;
  int fo = idx % 14;
  int co = (idx / 14) % 128;
  int t  = idx / (14 * 128);
  size_t bi = ((size_t)(t + 1) * 30 + 2 * fo + 1) * 128 + co;
  float v = (bf2f(in[bi]) + bf2f(in[bi + 128])) * 0.5f;
  feat[((size_t)(boff + t)) * 1792 + co * 14 + fo] = v;
}

// ---------------- MFMA GEMM, fp32 in (bf16 convert in staging) -------------
// C[M,N] = A[M,K] * W[N,K]^T. BM=128, BN=64, BK=32. Requires K%32==0, N%64==0.
// EPI: 0 none; 1 relu(v*sc[n]/sqrt(1+eps)+bi[n]).
template<int EPI>
__global__ __launch_bounds__(256)
void gemm_mfma(const float* __restrict__ A, int lda,
               const float* __restrict__ W, float* __restrict__ C,
               int M, int N, int K,
               const float* __restrict__ sc, const float* __restrict__ bi)
{
  __shared__ alignas(16) short A_s[4 * 128 * 8];   // [q][row][8] q-major
  __shared__ alignas(16) short B_s[4 * 64 * 8];
  const int tid  = threadIdx.x;
  const int lane = tid & 63, w = tid >> 6;
  const int wm = w >> 1, wn = w & 1;
  const int m0 = blockIdx.y * 128, n0 = blockIdx.x * 64;

  int mrow[2];
  #pragma unroll
  for (int j = 0; j < 2; ++j) {
    int slot = j * 256 + tid;
    int row = slot & 127;
    int m = m0 + row; if (m >= M) m = M - 1;
    mrow[j] = m;
  }

  f32x4 acc[4][2];
  #pragma unroll
  for (int i = 0; i < 4; ++i)
    #pragma unroll
    for (int jn = 0; jn < 2; ++jn) acc[i][jn] = (f32x4){0.f, 0.f, 0.f, 0.f};

  for (int k0 = 0; k0 < K; k0 += 32) {
    __syncthreads();
    #pragma unroll
    for (int j = 0; j < 2; ++j) {
      int slot = j * 256 + tid;
      int q = slot >> 7;
      const float* src = A + (size_t)mrow[j] * lda + k0 + q * 8;
      short8b s;
      #pragma unroll
      for (int e = 0; e < 8; ++e) s[e] = (short)f2bf(src[e]);
      *(short8b*)&A_s[slot * 8] = s;
    }
    {
      int q = tid >> 6, nn = tid & 63;
      const float* src = W + (size_t)(n0 + nn) * K + k0 + q * 8;
      short8b s;
      #pragma unroll
      for (int e = 0; e < 8; ++e) s[e] = (short)f2bf(src[e]);
      *(short8b*)&B_s[tid * 8] = s;
    }
    __syncthreads();
    const int lr = lane & 15, lq = lane >> 4;
    short8b a[4], b[2];
    #pragma unroll
    for (int i = 0; i < 4; ++i)
      a[i] = *(const short8b*)&A_s[(lq * 128 + wm * 64 + i * 16 + lr) * 8];
    #pragma unroll
    for (int jn = 0; jn < 2; ++jn)
      b[jn] = *(const short8b*)&B_s[(lq * 64 + wn * 32 + jn * 16 + lr) * 8];
    #pragma unroll
    for (int i = 0; i < 4; ++i)
      #pragma unroll
      for (int jn = 0; jn < 2; ++jn)
        acc[i][jn] = __builtin_amdgcn_mfma_f32_16x16x32_bf16(
            a[i], b[jn], acc[i][jn], 0, 0, 0);
  }
  const float inv = rsqrtf(1.f + 1e-5f);
  const int lr = lane & 15, lq = lane >> 4;
  #pragma unroll
  for (int jn = 0; jn < 2; ++jn) {
    int col = n0 + wn * 32 + jn * 16 + lr;
    float scv = (EPI == 1) ? sc[col] * inv : 0.f;
    float biv = (EPI == 1) ? bi[col] : 0.f;
    #pragma unroll
    for (int i = 0; i < 4; ++i) {
      #pragma unroll
      for (int r = 0; r < 4; ++r) {
        int row = m0 + wm * 64 + i * 16 + lq * 4 + r;
        if (row < M) {
          float v = acc[i][jn][r];
          if (EPI == 1) v = fmaxf(fmaf(v, scv, biv), 0.f);
          C[(size_t)row * N + col] = v;
        }
      }
    }
  }
}

// ---------------- generic tiled fp32 GEMM (small GEMMs) --------------------
// EPI: 0 none; 2 softplus(v+bi[n]); 3 sigmoid(v+bi[n]).  K % 16 == 0.
template<int EPI>
__global__ __launch_bounds__(256)
void gemm_nt(const float* __restrict__ A, int lda,
             const float* __restrict__ W,
             float* __restrict__ C, int M, int N, int K,
             const float* __restrict__ sc, const float* __restrict__ bi)
{
  __shared__ float As[16][68];
  __shared__ float Bs[16][68];
  const int tid = threadIdx.x;
  const int m0 = blockIdx.y * 64, n0 = blockIdx.x * 64;
  const int tx = tid % 16, ty = tid / 16;
  const int lr = tid / 4, lk = (tid % 4) * 4;
  float acc[4][4];
  #pragma unroll
  for (int i = 0; i < 4; ++i)
    #pragma unroll
    for (int j = 0; j < 4; ++j) acc[i][j] = 0.f;

  for (int k0 = 0; k0 < K; k0 += 16) {
    __syncthreads();
    {
      int m = m0 + lr;
      float4 a = make_float4(0.f, 0.f, 0.f, 0.f);
      if (m < M) a = *(const float4*)(A + (size_t)m * lda + k0 + lk);
      As[lk + 0][lr] = a.x; As[lk + 1][lr] = a.y;
      As[lk + 2][lr] = a.z; As[lk + 3][lr] = a.w;
      int n = n0 + lr;
      float4 wv = make_float4(0.f, 0.f, 0.f, 0.f);
      if (n < N) wv = *(const float4*)(W + (size_t)n * K + k0 + lk);
      Bs[lk + 0][lr] = wv.x; Bs[lk + 1][lr] = wv.y;
      Bs[lk + 2][lr] = wv.z; Bs[lk + 3][lr] = wv.w;
    }
    __syncthreads();
    #pragma unroll
    for (int kk = 0; kk < 16; ++kk) {
      float4 av = *(const float4*)(&As[kk][ty * 4]);
      float4 bv = *(const float4*)(&Bs[kk][tx * 4]);
      float a[4] = {av.x, av.y, av.z, av.w};
      float bb[4] = {bv.x, bv.y, bv.z, bv.w};
      #pragma unroll
      for (int i = 0; i < 4; ++i)
        #pragma unroll
        for (int j = 0; j < 4; ++j)
          acc[i][j] = fmaf(a[i], bb[j], acc[i][j]);
    }
  }
  #pragma unroll
  for (int i = 0; i < 4; ++i) {
    int m = m0 + ty * 4 + i;
    if (m >= M) continue;
    #pragma unroll
    for (int j = 0; j < 4; ++j) {
      int n = n0 + tx * 4 + j;
      if (n >= N) continue;
      float v = acc[i][j];
      if (EPI == 2) {
        float x = v + bi[n];
        v = (x > 20.f) ? x : log1pf(__expf(x));
      } else if (EPI == 3) {
        v = sigmoidf_(v + bi[n]);
      }
      C[(size_t)m * N + n] = v;
    }
  }
}

// ---------------- LayerNorm over 768 features (safe in-place) --------------
__global__ __launch_bounds__(256)
void layernorm768(const float* __restrict__ in, const float* __restrict__ g,
                  const float* __restrict__ b, float* __restrict__ out)
{
  const int row = blockIdx.x;
  const float* x = in + (size_t)row * 768;
  const int tid = threadIdx.x;
  float v0 = x[tid], v1 = x[tid + 256], v2 = x[tid + 512];
  float s = v0 + v1 + v2;
  float q = v0 * v0 + v1 * v1 + v2 * v2;
  #pragma unroll
  for (int off = 32; off >= 1; off >>= 1) {
    s += __shfl_down(s, off);
    q += __shfl_down(q, off);
  }
  __shared__ float rs[4], rq[4];
  int wave = tid >> 6;
  if ((tid & 63) == 0) { rs[wave] = s; rq[wave] = q; }
  __syncthreads();
  float ts = rs[0] + rs[1] + rs[2] + rs[3];
  float tq = rq[0] + rq[1] + rq[2] + rq[3];
  float mu = ts * (1.f / 768.f);
  float var = tq * (1.f / 768.f) - mu * mu;
  float rstd = rsqrtf(var + 1e-5f);
  float* o = out + (size_t)row * 768;
  o[tid]       = (v0 - mu) * rstd * g[tid]       + b[tid];
  o[tid + 256] = (v1 - mu) * rstd * g[tid + 256] + b[tid + 256];
  o[tid + 512] = (v2 - mu) * rstd * g[tid + 512] + b[tid + 512];
}

// ---------------- depthwise causal conv (K=4) + SiLU -----------------------
__global__ __launch_bounds__(256)
void dwconv_silu(const float* __restrict__ xz, const float* __restrict__ cw,
                 const float* __restrict__ cb, float* __restrict__ xmc, int total)
{
  int idx = blockIdx.x * 256 + threadIdx.x;
  if (idx >= total) return;
  int d = idx % 1536;
  int t = (idx / 1536) % 1000;
  int b = idx / (1536 * 1000);
  float acc = cb[d];
  #pragma unroll
  for (int j = 0; j < 4; ++j) {
    int tt = t - 3 + j;
    if (tt >= 0)
      acc = fmaf(cw[d * 4 + j], xz[((size_t)(b * 1000 + tt)) * 3072 + d], acc);
  }
  xmc[idx] = acc * sigmoidf_(acc);
}

// ---------------- chunked parallel scan (3 passes) -------------------------
// Recurrence per (b,d,n): h = exp(dt*A[n])*h + dt*x*B[n]; y = sum_n h*C[n].
// L=100 steps/chunk, NC=10 chunks.
__global__ __launch_bounds__(64)
void scan_p1(const float* __restrict__ dt, const float* __restrict__ xmc,
             const float* __restrict__ dbl, const float* __restrict__ A_log,
             float* __restrict__ hend, float* __restrict__ pend)
{
  const int d = blockIdx.x * 64 + threadIdx.x;
  const int b = blockIdx.y;
  const int c = blockIdx.z;
  float A[16], h[16];
  #pragma unroll
  for (int n = 0; n < 16; ++n) {
    A[n] = -__expf(A_log[d * 16 + n]);
    h[n] = 0.f;
  }
  float S = 0.f;
  const int t0 = c * 100;
  for (int t = t0; t < t0 + 100; ++t) {
    size_t r = (size_t)b * 1000 + t;
    float dtv = dt[r * 1536 + d];
    float xv  = xmc[r * 1536 + d];
    const float* bc = dbl + r * 80;
    float dtx = dtv * xv;
    S += dtv;
    #pragma unroll
    for (int n = 0; n < 16; ++n)
      h[n] = fmaf(__expf(dtv * A[n]), h[n], dtx * bc[48 + n]);
  }
  size_t base = (((size_t)c * 4 + b) * 1536 + d) * 16;
  #pragma unroll
  for (int n = 0; n < 16; ++n) {
    hend[base + n] = h[n];
    pend[base + n] = __expf(S * A[n]);   // prod of a over chunk
  }
}

__global__ __launch_bounds__(256)
void scan_p2(const float* __restrict__ hend, const float* __restrict__ pend,
             float* __restrict__ hin)
{
  int gid = blockIdx.x * 256 + threadIdx.x;   // (b*1536+d), 6144 total
  if (gid >= 6144) return;
  float cur[16];
  #pragma unroll
  for (int n = 0; n < 16; ++n) cur[n] = 0.f;
  for (int c = 0; c < 10; ++c) {
    size_t base = ((size_t)c * 6144 + gid) * 16;
    #pragma unroll
    for (int n = 0; n < 16; ++n) {
      hin[base + n] = cur[n];
      cur[n] = fmaf(pend[base + n], cur[n], hend[base + n]);
    }
  }
}

// pass 3: replay chunk with correct h_in; write g = (y + x*D)*silu(z) in place
// over dt (single-owner element aliasing).
__global__ __launch_bounds__(64)
void scan_p3(const float* __restrict__ dt, const float* __restrict__ xmc,
             const float* __restrict__ dbl, const float* __restrict__ xz,
             const float* __restrict__ A_log, const float* __restrict__ Dp,
             const float* __restrict__ hin, float* __restrict__ g_out)
{
  const int d = blockIdx.x * 64 + threadIdx.x;
  const int b = blockIdx.y;
  const int c = blockIdx.z;
  float A[16], h[16];
  size_t base = (((size_t)c * 4 + b) * 1536 + d) * 16;
  #pragma unroll
  for (int n = 0; n < 16; ++n) {
    A[n] = -__expf(A_log[d * 16 + n]);
    h[n] = hin[base + n];
  }
  const float Dd = Dp[d];
  const int t0 = c * 100;
  for (int t = t0; t < t0 + 100; ++t) {
    size_t r = (size_t)b * 1000 + t;
    float dtv = dt[r * 1536 + d];
    float xv  = xmc[r * 1536 + d];
    float zv  = xz[r * 3072 + 1536 + d];
    const float* bc = dbl + r * 80;
    float dtx = dtv * xv;
    float y = 0.f;
    #pragma unroll
    for (int n = 0; n < 16; ++n) {
      float hn = fmaf(__expf(dtv * A[n]), h[n], dtx * bc[48 + n]);
      h[n] = hn;
      y = fmaf(hn, bc[64 + n], y);
    }
    y = fmaf(xv, Dd, y);
    g_out[r * 1536 + d] = y * (zv * sigmoidf_(zv));
  }
}

// ---------------------------------------------------------------------------
extern "C" void kernel_launch(void* const* d_in, const int* in_sizes, int n_in,
                              void* d_out, int out_size, void* d_ws, size_t ws_size,
                              hipStream_t stream)
{
  const float* x    = (const float*)d_in[0];
  const float* cw1[4] = {(const float*)d_in[1],  (const float*)d_in[7],
                         (const float*)d_in[13], (const float*)d_in[19]};
  const float* cg1[4] = {(const float*)d_in[2],  (const float*)d_in[8],
                         (const float*)d_in[14], (const float*)d_in[20]};
  const float* cb1[4] = {(const float*)d_in[3],  (const float*)d_in[9],
                         (const float*)d_in[15], (const float*)d_in[21]};
  const float* cw2[4] = {(const float*)d_in[4],  (const float*)d_in[10],
                         (const float*)d_in[16], (const float*)d_in[22]};
  const float* cg2[4] = {(const float*)d_in[5],  (const float*)d_in[11],
                         (const float*)d_in[17], (const float*)d_in[23]};
  const float* cb2[4] = {(const float*)d_in[6],  (const float*)d_in[12],
                         (const float*)d_in[18], (const float*)d_in[24]};
  const float* fc5w = (const float*)d_in[25]; const float* bn5g = (const float*)d_in[26]; const float* bn5b = (const float*)d_in[27];
  const float* lng  = (const float*)d_in[28]; const float* lnb  = (const float*)d_in[29];
  const float* minw = (const float*)d_in[30]; const float* mcw  = (const float*)d_in[31]; const float* mcb  = (const float*)d_in[32];
  const float* mxw  = (const float*)d_in[33]; const float* mdtw = (const float*)d_in[34]; const float* mdtb = (const float*)d_in[35];
  const float* malog= (const float*)d_in[36]; const float* mD   = (const float*)d_in[37]; const float* moutw= (const float*)d_in[38];
  const float* pw   = (const float*)d_in[39]; const float* pb   = (const float*)d_in[40];

  char* ws = (char*)d_ws;
  // conv phase:
  unsigned short* bufA = (unsigned short*)(ws + 0);           // 30 MB
  unsigned short* bufB = (unsigned short*)(ws + 30000000);    // 30 MB
  unsigned short* w1b = (unsigned short*)(ws + 60000000);
  unsigned short* w2a = (unsigned short*)(ws + 60100000);
  unsigned short* w2b = (unsigned short*)(ws + 60200000);
  unsigned short* w3a = (unsigned short*)(ws + 60300000);
  unsigned short* w3b = (unsigned short*)(ws + 60450000);
  unsigned short* w4a = (unsigned short*)(ws + 60650000);
  unsigned short* w4b = (unsigned short*)(ws + 60900000);
  float* feat = (float*)(ws + 61500000);                      // [4000][1792] f32
  float* hfc  = (float*)(ws + 90200000);                      // [4000][768]
  // post-conv phase:
  float* xzb  = (float*)(ws + 0);                             // [4000][3072]
  float* xmc  = (float*)(ws + 49200000);                      // [4000][1536]
  float* dblb = (float*)(ws + 74000000);                      // [4000][80]
  float* hend = (float*)(ws + 76000000);                      // [10][4][1536][16]
  float* pend = (float*)(ws + 81000000);
  float* hin  = (float*)(ws + 86000000);                      // ends 89.93M
  float* mam  = (float*)(ws + 75500000);                      // [4000][768] (after scan temps dead)
  float* dtb  = (float*)(ws + 102500000);                     // [4000][1536]; scan in-place

  dim3 blk(256);

  // ---- conv weight transforms ----
  {
    struct WT { const float* src; unsigned short* dst; int CO, CIN, COp, Cpin; };
    WT wt[7] = {
      {cw2[0], w1b,  48,  48,  64,  64},
      {cw1[1], w2a,  64,  48,  64,  64},
      {cw2[1], w2b,  64,  64,  64,  64},
      {cw1[2], w3a,  96,  64,  96,  64},
      {cw2[2], w3b,  96,  96,  96,  96},
      {cw1[3], w4a, 128,  96, 128,  96},
      {cw2[3], w4b, 128, 128, 128, 128},
    };
    for (int i = 0; i < 7; ++i) {
      int total = 9 * wt[i].COp * wt[i].Cpin;
      wt_transform<<<dim3((total + 255) / 256), blk, 0, stream>>>(
          wt[i].src, wt[i].dst, wt[i].CO, wt[i].CIN, wt[i].COp, wt[i].Cpin, total);
    }
  }

  auto zb = [&](unsigned short* buf, int F, int Cp) {
    int total = 2 * (F + 2) * Cp + 2000 * Cp;
    zero_border<<<dim3((total + 255) / 256), blk, 0, stream>>>(buf, F, Cp, total);
  };
  auto pool = [&](const unsigned short* in, unsigned short* out,
                  int Fin, int Fo, int Cp) {
    int total4 = 1000 * Fo * Cp / 4;
    pool_ch<<<dim3((total4 + 255) / 256), blk, 0, stream>>>(in, out, Fin, Fo, Cp, total4);
  };

  for (int b = 0; b < 4; ++b) {
    const float* xb = x + (size_t)b * 1000 * 229;
    zb(bufA, 229, 64);
    conv1_first<<<dim3(58, 1000), blk, 0, stream>>>(xb, cw1[0], cg1[0], cb1[0], bufA);
    zb(bufB, 229, 64);
    conv_mfma<64, 64, 229, 128, 48><<<dim3(1790), blk, 0, stream>>>(
        bufA, w1b, cg2[0], cb2[0], bufB, 229000);
    zb(bufA, 114, 64);
    pool(bufB, bufA, 229, 114, 64);
    zb(bufB, 114, 64);
    conv_mfma<64, 64, 114, 128, 64><<<dim3(891), blk, 0, stream>>>(
        bufA, w2a, cg1[1], cb1[1], bufB, 114000);
    zb(bufA, 114, 64);
    conv_mfma<64, 64, 114, 128, 64><<<dim3(891), blk, 0, stream>>>(
        bufB, w2b, cg2[1], cb2[1], bufA, 114000);
    zb(bufB, 57, 64);
    pool(bufA, bufB, 114, 57, 64);
    zb(bufA, 57, 96);
    conv_mfma<96, 64, 57, 128, 96><<<dim3(446), blk, 0, stream>>>(
        bufB, w3a, cg1[2], cb1[2], bufA, 57000);
    zb(bufB, 57, 96);
    conv_mfma<96, 96, 57, 128, 96><<<dim3(446), blk, 0, stream>>>(
        bufA, w3b, cg2[2], cb2[2], bufB, 57000);
    zb(bufA, 28, 96);
    pool(bufB, bufA, 57, 28, 96);
    zb(bufB, 28, 128);
    conv_mfma<128, 96, 28, 64, 128><<<dim3(438), blk, 0, stream>>>(
        bufA, w4a, cg1[3], cb1[3], bufB, 28000);
    zb(bufA, 28, 128);
    conv_mfma<128, 128, 28, 64, 128><<<dim3(438), blk, 0, stream>>>(
        bufB, w4b, cg2[3], cb2[3], bufA, 28000);
    pool4_trans<<<dim3((1000 * 128 * 14 + 255) / 256), blk, 0, stream>>>(
        bufA, feat, b * 1000);
  }

  // ---- fc5 + BN + ReLU (MFMA, fp32 in) ----
  gemm_mfma<1><<<dim3(12, 32), blk, 0, stream>>>(feat, 1792, fc5w, hfc, 4000, 768, 1792, bn5g, bn5b);
  // ---- LayerNorm (in-place) ----
  layernorm768<<<dim3(4000), blk, 0, stream>>>(hfc, lng, lnb, hfc);
  // ---- mamba in_proj (MFMA) ----
  gemm_mfma<0><<<dim3(48, 32), blk, 0, stream>>>(hfc, 768, minw, xzb, 4000, 3072, 768, nullptr, nullptr);
  // ---- depthwise causal conv + silu ----
  dwconv_silu<<<dim3((6144000 + 255) / 256), blk, 0, stream>>>(xzb, mcw, mcb, xmc, 6144000);
  // ---- x_proj (fp32) ----
  gemm_nt<0><<<dim3(2, 63), blk, 0, stream>>>(xmc, 1536, mxw, dblb, 4000, 80, 1536, nullptr, nullptr);
  // ---- dt = softplus(dbl[:, :48] @ dt_w^T + dt_b) (fp32) ----
  gemm_nt<2><<<dim3(24, 63), blk, 0, stream>>>(dblb, 80, mdtw, dtb, 4000, 1536, 48, nullptr, mdtb);
  // ---- chunked parallel scan (writes g into dtb in place) ----
  scan_p1<<<dim3(24, 4, 10), dim3(64), 0, stream>>>(dtb, xmc, dblb, malog, hend, pend);
  scan_p2<<<dim3(24), blk, 0, stream>>>(hend, pend, hin);
  scan_p3<<<dim3(24, 4, 10), dim3(64), 0, stream>>>(dtb, xmc, dblb, xzb, malog, mD, hin, dtb);
  // ---- out_proj (MFMA) ----
  gemm_mfma<0><<<dim3(12, 32), blk, 0, stream>>>(dtb, 1536, moutw, mam, 4000, 768, 1536, nullptr, nullptr);
  // ---- final proj + sigmoid -> d_out (fp32) ----
  gemm_nt<3><<<dim3(2, 63), blk, 0, stream>>>(mam, 768, pw, (float*)d_out, 4000, 88, 768, nullptr, pb);
}

// Round 10
// 2108.196 us; speedup vs baseline: 4.2910x; 1.0826x over previous
//
#include <hip/hip_runtime.h>
#include <math.h>

// ---------------------------------------------------------------------------
// Round 10: global_load_lds (width 16) staging for conv_mfma and new
// bf16-native gemm_bf16 (fc5/in_proj/out_proj); producers emit bf16 directly
// (pool4_trans, LayerNorm, scan_p3); weights pre-converted once. Scan NC=8.
// ---------------------------------------------------------------------------

static __device__ __forceinline__ float sigmoidf_(float x) {
  return 1.f / (1.f + __expf(-x));
}
static __device__ __forceinline__ unsigned short f2bf(float f) {
  union { float f; unsigned int u; } c; c.f = f;
  unsigned int u = c.u;
  unsigned int r = (u + 0x7FFFu + ((u >> 16) & 1u)) >> 16;   // RTNE
  return (unsigned short)r;
}
static __device__ __forceinline__ float bf2f(unsigned short b) {
  union { unsigned int u; float f; } c; c.u = ((unsigned int)b) << 16;
  return c.f;
}
// async global->LDS, 16B per lane; lds ptr must be wave-uniform base.
static __device__ __forceinline__ void glds16(const void* g, void* l) {
  __builtin_amdgcn_global_load_lds(
      (const __attribute__((address_space(1))) unsigned int*)g,
      (__attribute__((address_space(3))) unsigned int*)l, 16, 0, 0);
}

typedef __attribute__((ext_vector_type(8))) short short8b;
typedef __attribute__((ext_vector_type(4))) float f32x4;
typedef __attribute__((ext_vector_type(4))) unsigned short ushort4b;

// ---------------- zero the padded borders of an act buffer -----------------
__global__ __launch_bounds__(256)
void zero_border(unsigned short* __restrict__ buf, int F, int Cp, int total)
{
  int idx = blockIdx.x * 256 + threadIdx.x;
  if (idx >= total) return;
  int rowelems = (F + 2) * Cp;
  if (idx < 2 * rowelems) {
    int r = idx / rowelems;
    int k = idx % rowelems;
    buf[(size_t)(r * 1001) * rowelems + k] = 0;
  } else {
    int j = idx - 2 * rowelems;
    int t = j / (2 * Cp) + 1;
    int side = (j / Cp) & 1;
    int c = j % Cp;
    buf[((size_t)t * (F + 2) + (side ? F + 1 : 0)) * Cp + c] = 0;
  }
}

// ---------------- weight transform: [CO][CIN][3][3] f32 -> [9][COp][Cpin] bf16
__global__ __launch_bounds__(256)
void wt_transform(const float* __restrict__ W, unsigned short* __restrict__ dst,
                  int CO, int CIN, int COp, int Cpin, int total)
{
  int idx = blockIdx.x * 256 + threadIdx.x;
  if (idx >= total) return;
  int ci = idx % Cpin;
  int co = (idx / Cpin) % COp;
  int s  = idx / (Cpin * COp);
  float v = (co < CO && ci < CIN) ? W[((size_t)co * CIN + ci) * 9 + s] : 0.f;
  dst[idx] = f2bf(v);
}

// ---------------- flat fp32 -> bf16 convert (GEMM weights) -----------------
__global__ __launch_bounds__(256)
void wcvt(const float* __restrict__ src, unsigned short* __restrict__ dst, int total)
{
  int i = blockIdx.x * 256 + threadIdx.x;
  if (i < total) dst[i] = f2bf(src[i]);
}

// ---------------- first conv (CIN=1) fp32 -> padded bf16 -------------------
__global__ __launch_bounds__(256)
void conv1_first(const float* __restrict__ x, const float* __restrict__ W,
                 const float* __restrict__ g, const float* __restrict__ bt,
                 unsigned short* __restrict__ out)
{
  __shared__ float ws[48 * 9];
  __shared__ float xs[3][6];
  const int tid = threadIdx.x;
  const int f0 = blockIdx.x * 4;
  const int t  = blockIdx.y;
  for (int i = tid; i < 48 * 9; i += 256) ws[i] = W[i];
  if (tid < 18) {
    int r = tid / 6, c = tid % 6;
    int ff = f0 - 1 + c, tt = t - 1 + r;
    xs[r][c] = (ff >= 0 && ff < 229 && tt >= 0 && tt < 1000)
                   ? x[tt * 229 + ff] : 0.f;
  }
  __syncthreads();
  const int co = tid & 63;
  const int fi = tid >> 6;
  const int f  = f0 + fi;
  float v = 0.f;
  if (co < 48) {
    float acc = 0.f;
    #pragma unroll
    for (int ky = 0; ky < 3; ++ky)
      #pragma unroll
      for (int kx = 0; kx < 3; ++kx)
        acc = fmaf(ws[co * 9 + ky * 3 + kx], xs[ky][fi + kx], acc);
    const float inv = rsqrtf(1.f + 1e-5f);
    v = fmaxf(fmaf(acc, g[co] * inv, bt[co]), 0.f);
  }
  if (f < 229)
    out[((size_t)(t + 1) * 231 + f + 1) * 64 + co] = f2bf(v);
}

// ---------------- MFMA shift-GEMM conv3x3 + BN + ReLU ----------------------
// global_load_lds staging: LDS slot = q-major linear index, lane-linear per
// wave (dest = wave-uniform base + lane*16B); global src per-lane.
template<int COp, int Cpin, int F, int BM, int CO>
__global__ __launch_bounds__(256)
void conv_mfma(const unsigned short* __restrict__ act,
               const unsigned short* __restrict__ W9,
               const float* __restrict__ gam, const float* __restrict__ bet,
               unsigned short* __restrict__ out, int M)
{
  static_assert(BM == 64 || BM == 128, "");
  constexpr int MI = BM / 32;
  constexpr int NJ = COp / 32;
  constexpr int KSTEPS = Cpin / 32;
  __shared__ alignas(16) short A_s[4 * BM * 8];
  __shared__ alignas(16) short B_s[4 * COp * 8];

  const int tid  = threadIdx.x;
  const int lane = tid & 63, w = tid >> 6;
  const int wm = w >> 1, wn = w & 1;
  const int m0 = blockIdx.x * BM;
  const int wbase = tid & 192;         // wave-uniform slot base within 256

  int prA[BM / 64];
  #pragma unroll
  for (int j = 0; j < BM / 64; ++j) {
    int slot = j * 256 + tid;
    int row  = slot % BM;
    int pos  = m0 + row; if (pos >= M) pos = M - 1;
    int t = pos / F, f = pos - t * F;
    prA[j] = (t + 1) * (F + 2) + (f + 1);
  }

  f32x4 acc[MI][NJ];
  #pragma unroll
  for (int i = 0; i < MI; ++i)
    #pragma unroll
    for (int jn = 0; jn < NJ; ++jn) acc[i][jn] = (f32x4){0.f, 0.f, 0.f, 0.f};

  for (int s = 0; s < 9; ++s) {
    const int soff = (s / 3 - 1) * (F + 2) + (s % 3) - 1;
    for (int kc = 0; kc < KSTEPS; ++kc) {
      __syncthreads();
      #pragma unroll
      for (int j = 0; j < BM / 64; ++j) {
        int slot = j * 256 + tid;
        int q = slot / BM;
        glds16(&act[(size_t)(prA[j] + soff) * Cpin + kc * 32 + q * 8],
               &A_s[(j * 256 + wbase) * 8]);
      }
      #pragma unroll
      for (int sb = 0; sb < (COp * 4 + 255) / 256; ++sb) {
        int slot = sb * 256 + tid;
        if (slot < COp * 4) {              // wave-uniform for COp in {64,96,128}
          int q = slot / COp, co = slot % COp;
          glds16(&W9[((size_t)(s * COp + co)) * Cpin + kc * 32 + q * 8],
                 &B_s[(sb * 256 + wbase) * 8]);
        }
      }
      __syncthreads();
      const int lr = lane & 15, lq = lane >> 4;
      short8b a[MI], b[NJ];
      #pragma unroll
      for (int i = 0; i < MI; ++i)
        a[i] = *(const short8b*)&A_s[(lq * BM + wm * (BM / 2) + i * 16 + lr) * 8];
      #pragma unroll
      for (int jn = 0; jn < NJ; ++jn)
        b[jn] = *(const short8b*)&B_s[(lq * COp + wn * (COp / 2) + jn * 16 + lr) * 8];
      #pragma unroll
      for (int i = 0; i < MI; ++i)
        #pragma unroll
        for (int jn = 0; jn < NJ; ++jn)
          acc[i][jn] = __builtin_amdgcn_mfma_f32_16x16x32_bf16(
              a[i], b[jn], acc[i][jn], 0, 0, 0);
    }
  }
  const float inv = rsqrtf(1.f + 1e-5f);
  const int lr = lane & 15, lq = lane >> 4;
  #pragma unroll
  for (int jn = 0; jn < NJ; ++jn) {
    int co = wn * (COp / 2) + jn * 16 + lr;
    float sc = (co < CO) ? gam[co] * inv : 0.f;
    float bi = (co < CO) ? bet[co] : 0.f;
    #pragma unroll
    for (int i = 0; i < MI; ++i) {
      #pragma unroll
      for (int r = 0; r < 4; ++r) {
        int pos = m0 + wm * (BM / 2) + i * 16 + lq * 4 + r;
        if (pos < M) {
          int t = pos / F, f = pos - t * F;
          float v = fmaxf(fmaf(acc[i][jn][r], sc, bi), 0.f);
          out[((size_t)(t + 1) * (F + 2) + f + 1) * COp + co] = f2bf(v);
        }
      }
    }
  }
}

// ---------------- avg-pool /2 along F, padded bf16 -> padded bf16 ----------
__global__ __launch_bounds__(256)
void pool_ch(const unsigned short* __restrict__ in, unsigned short* __restrict__ out,
             int Fin, int Fo, int Cp, int total4)
{
  int idx = blockIdx.x * 256 + threadIdx.x;
  if (idx >= total4) return;
  int cg = Cp / 4;
  int c4 = idx % cg;
  int fo = (idx / cg) % Fo;
  int t  = idx / (cg * Fo);
  size_t bi = ((size_t)(t + 1) * (Fin + 2) + 2 * fo + 1) * Cp + c4 * 4;
  ushort4b a = *(const ushort4b*)&in[bi];
  ushort4b b = *(const ushort4b*)&in[bi + Cp];
  ushort4b o;
  #pragma unroll
  for (int e = 0; e < 4; ++e)
    o[e] = f2bf((bf2f(a[e]) + bf2f(b[e])) * 0.5f);
  *(ushort4b*)&out[((size_t)(t + 1) * (Fo + 2) + fo + 1) * Cp + c4 * 4] = o;
}

// ---------------- final pool -> transposed bf16 features -------------------
__global__ __launch_bounds__(256)
void pool4_trans(const unsigned short* __restrict__ in,
                 unsigned short* __restrict__ feat, int boff)
{
  int idx = blockIdx.x * 256 + threadIdx.x;
  if (idx >= 1000 * 128 * 14) return;
  int fo = idx % 14;
  int co = (idx / 14) % 128;
  int t  = idx / (14 * 128);
  size_t bi = ((size_t)(t + 1) * 30 + 2 * fo + 1) * 128 + co;
  float v = (bf2f(in[bi]) + bf2f(in[bi + 128])) * 0.5f;
  feat[((size_t)(boff + t)) * 1792 + co * 14 + fo] = f2bf(v);
}

// ---------------- bf16 MFMA GEMM with global_load_lds ----------------------
// C[M,N] = A[M,K](bf16) * W[N,K]^T(bf16), fp32 out. BM=128,BN=64,BK=32.
// K%32==0, N%64==0. EPI: 0 none; 1 relu(v*sc[n]/sqrt(1+eps)+bi[n]).
template<int EPI>
__global__ __launch_bounds__(256)
void gemm_bf16(const unsigned short* __restrict__ A, int lda,
               const unsigned short* __restrict__ W, float* __restrict__ C,
               int M, int N, int K,
               const float* __restrict__ sc, const float* __restrict__ bi)
{
  __shared__ alignas(16) short A_s[4 * 128 * 8];   // [q][row][8] q-major
  __shared__ alignas(16) short B_s[4 * 64 * 8];
  const int tid  = threadIdx.x;
  const int lane = tid & 63, w = tid >> 6;
  const int wm = w >> 1, wn = w & 1;
  const int m0 = blockIdx.y * 128, n0 = blockIdx.x * 64;
  const int wbase = tid & 192;

  int mrow[2];
  #pragma unroll
  for (int j = 0; j < 2; ++j) {
    int slot = j * 256 + tid;
    int row = slot & 127;
    int m = m0 + row; if (m >= M) m = M - 1;
    mrow[j] = m;
  }
  const int bq = tid >> 6, bn = tid & 63;

  f32x4 acc[4][2];
  #pragma unroll
  for (int i = 0; i < 4; ++i)
    #pragma unroll
    for (int jn = 0; jn < 2; ++jn) acc[i][jn] = (f32x4){0.f, 0.f, 0.f, 0.f};

  for (int k0 = 0; k0 < K; k0 += 32) {
    __syncthreads();
    #pragma unroll
    for (int j = 0; j < 2; ++j) {
      int slot = j * 256 + tid;
      int q = slot >> 7;
      glds16(&A[(size_t)mrow[j] * lda + k0 + q * 8],
             &A_s[(j * 256 + wbase) * 8]);
    }
    glds16(&W[(size_t)(n0 + bn) * K + k0 + bq * 8], &B_s[wbase * 8]);
    __syncthreads();
    const int lr = lane & 15, lq = lane >> 4;
    short8b a[4], b[2];
    #pragma unroll
    for (int i = 0; i < 4; ++i)
      a[i] = *(const short8b*)&A_s[(lq * 128 + wm * 64 + i * 16 + lr) * 8];
    #pragma unroll
    for (int jn = 0; jn < 2; ++jn)
      b[jn] = *(const short8b*)&B_s[(lq * 64 + wn * 32 + jn * 16 + lr) * 8];
    #pragma unroll
    for (int i = 0; i < 4; ++i)
      #pragma unroll
      for (int jn = 0; jn < 2; ++jn)
        acc[i][jn] = __builtin_amdgcn_mfma_f32_16x16x32_bf16(
            a[i], b[jn], acc[i][jn], 0, 0, 0);
  }
  const float inv = rsqrtf(1.f + 1e-5f);
  const int lr = lane & 15, lq = lane >> 4;
  #pragma unroll
  for (int jn = 0; jn < 2; ++jn) {
    int col = n0 + wn * 32 + jn * 16 + lr;
    float scv = (EPI == 1) ? sc[col] * inv : 0.f;
    float biv = (EPI == 1) ? bi[col] : 0.f;
    #pragma unroll
    for (int i = 0; i < 4; ++i) {
      #pragma unroll
      for (int r = 0; r < 4; ++r) {
        int row = m0 + wm * 64 + i * 16 + lq * 4 + r;
        if (row < M) {
          float v = acc[i][jn][r];
          if (EPI == 1) v = fmaxf(fmaf(v, scv, biv), 0.f);
          C[(size_t)row * N + col] = v;
        }
      }
    }
  }
}

// ---------------- generic tiled fp32 GEMM (small GEMMs) --------------------
// EPI: 0 none; 2 softplus(v+bi[n]); 3 sigmoid(v+bi[n]).  K % 16 == 0.
template<int EPI>
__global__ __launch_bounds__(256)
void gemm_nt(const float* __restrict__ A, int lda,
             const float* __restrict__ W,
             float* __restrict__ C, int M, int N, int K,
             const float* __restrict__ sc, const float* __restrict__ bi)
{
  __shared__ float As[16][68];
  __shared__ float Bs[16][68];
  const int tid = threadIdx.x;
  const int m0 = blockIdx.y * 64, n0 = blockIdx.x * 64;
  const int tx = tid % 16, ty = tid / 16;
  const int lr = tid / 4, lk = (tid % 4) * 4;
  float acc[4][4];
  #pragma unroll
  for (int i = 0; i < 4; ++i)
    #pragma unroll
    for (int j = 0; j < 4; ++j) acc[i][j] = 0.f;

  for (int k0 = 0; k0 < K; k0 += 16) {
    __syncthreads();
    {
      int m = m0 + lr;
      float4 a = make_float4(0.f, 0.f, 0.f, 0.f);
      if (m < M) a = *(const float4*)(A + (size_t)m * lda + k0 + lk);
      As[lk + 0][lr] = a.x; As[lk + 1][lr] = a.y;
      As[lk + 2][lr] = a.z; As[lk + 3][lr] = a.w;
      int n = n0 + lr;
      float4 wv = make_float4(0.f, 0.f, 0.f, 0.f);
      if (n < N) wv = *(const float4*)(W + (size_t)n * K + k0 + lk);
      Bs[lk + 0][lr] = wv.x; Bs[lk + 1][lr] = wv.y;
      Bs[lk + 2][lr] = wv.z; Bs[lk + 3][lr] = wv.w;
    }
    __syncthreads();
    #pragma unroll
    for (int kk = 0; kk < 16; ++kk) {
      float4 av = *(const float4*)(&As[kk][ty * 4]);
      float4 bv = *(const float4*)(&Bs[kk][tx * 4]);
      float a[4] = {av.x, av.y, av.z, av.w};
      float bb[4] = {bv.x, bv.y, bv.z, bv.w};
      #pragma unroll
      for (int i = 0; i < 4; ++i)
        #pragma unroll
        for (int j = 0; j < 4; ++j)
          acc[i][j] = fmaf(a[i], bb[j], acc[i][j]);
    }
  }
  #pragma unroll
  for (int i = 0; i < 4; ++i) {
    int m = m0 + ty * 4 + i;
    if (m >= M) continue;
    #pragma unroll
    for (int j = 0; j < 4; ++j) {
      int n = n0 + tx * 4 + j;
      if (n >= N) continue;
      float v = acc[i][j];
      if (EPI == 2) {
        float x = v + bi[n];
        v = (x > 20.f) ? x : log1pf(__expf(x));
      } else if (EPI == 3) {
        v = sigmoidf_(v + bi[n]);
      }
      C[(size_t)m * N + n] = v;
    }
  }
}

// ---------------- LayerNorm over 768 features, bf16 out --------------------
__global__ __launch_bounds__(256)
void layernorm768_bf(const float* __restrict__ in, const float* __restrict__ g,
                     const float* __restrict__ b, unsigned short* __restrict__ out)
{
  const int row = blockIdx.x;
  const float* x = in + (size_t)row * 768;
  const int tid = threadIdx.x;
  float v0 = x[tid], v1 = x[tid + 256], v2 = x[tid + 512];
  float s = v0 + v1 + v2;
  float q = v0 * v0 + v1 * v1 + v2 * v2;
  #pragma unroll
  for (int off = 32; off >= 1; off >>= 1) {
    s += __shfl_down(s, off);
    q += __shfl_down(q, off);
  }
  __shared__ float rs[4], rq[4];
  int wave = tid >> 6;
  if ((tid & 63) == 0) { rs[wave] = s; rq[wave] = q; }
  __syncthreads();
  float ts = rs[0] + rs[1] + rs[2] + rs[3];
  float tq = rq[0] + rq[1] + rq[2] + rq[3];
  float mu = ts * (1.f / 768.f);
  float var = tq * (1.f / 768.f) - mu * mu;
  float rstd = rsqrtf(var + 1e-5f);
  unsigned short* o = out + (size_t)row * 768;
  o[tid]       = f2bf((v0 - mu) * rstd * g[tid]       + b[tid]);
  o[tid + 256] = f2bf((v1 - mu) * rstd * g[tid + 256] + b[tid + 256]);
  o[tid + 512] = f2bf((v2 - mu) * rstd * g[tid + 512] + b[tid + 512]);
}

// ---------------- depthwise causal conv (K=4) + SiLU -----------------------
__global__ __launch_bounds__(256)
void dwconv_silu(const float* __restrict__ xz, const float* __restrict__ cw,
                 const float* __restrict__ cb, float* __restrict__ xmc, int total)
{
  int idx = blockIdx.x * 256 + threadIdx.x;
  if (idx >= total) return;
  int d = idx % 1536;
  int t = (idx / 1536) % 1000;
  int b = idx / (1536 * 1000);
  float acc = cb[d];
  #pragma unroll
  for (int j = 0; j < 4; ++j) {
    int tt = t - 3 + j;
    if (tt >= 0)
      acc = fmaf(cw[d * 4 + j], xz[((size_t)(b * 1000 + tt)) * 3072 + d], acc);
  }
  xmc[idx] = acc * sigmoidf_(acc);
}

// ---------------- chunked parallel scan (3 passes, NC=8, L=125) ------------
__global__ __launch_bounds__(64)
void scan_p1(const float* __restrict__ dt, const float* __restrict__ xmc,
             const float* __restrict__ dbl, const float* __restrict__ A_log,
             float* __restrict__ hend, float* __restrict__ pend)
{
  const int d = blockIdx.x * 64 + threadIdx.x;
  const int b = blockIdx.y;
  const int c = blockIdx.z;
  float A[16], h[16];
  #pragma unroll
  for (int n = 0; n < 16; ++n) {
    A[n] = -__expf(A_log[d * 16 + n]);
    h[n] = 0.f;
  }
  float S = 0.f;
  const int t0 = c * 125;
  for (int t = t0; t < t0 + 125; ++t) {
    size_t r = (size_t)b * 1000 + t;
    float dtv = dt[r * 1536 + d];
    float xv  = xmc[r * 1536 + d];
    const float* bc = dbl + r * 80;
    float dtx = dtv * xv;
    S += dtv;
    #pragma unroll
    for (int n = 0; n < 16; ++n)
      h[n] = fmaf(__expf(dtv * A[n]), h[n], dtx * bc[48 + n]);
  }
  size_t base = (((size_t)c * 4 + b) * 1536 + d) * 16;
  #pragma unroll
  for (int n = 0; n < 16; ++n) {
    hend[base + n] = h[n];
    pend[base + n] = __expf(S * A[n]);
  }
}

__global__ __launch_bounds__(256)
void scan_p2(const float* __restrict__ hend, const float* __restrict__ pend,
             float* __restrict__ hin)
{
  int gid = blockIdx.x * 256 + threadIdx.x;   // b*1536+d, 6144 total
  if (gid >= 6144) return;
  float cur[16];
  #pragma unroll
  for (int n = 0; n < 16; ++n) cur[n] = 0.f;
  for (int c = 0; c < 8; ++c) {
    size_t base = ((size_t)c * 6144 + gid) * 16;
    #pragma unroll
    for (int n = 0; n < 16; ++n) {
      hin[base + n] = cur[n];
      cur[n] = fmaf(pend[base + n], cur[n], hend[base + n]);
    }
  }
}

// pass 3: replay chunk with correct h_in; write g bf16.
__global__ __launch_bounds__(64)
void scan_p3(const float* __restrict__ dt, const float* __restrict__ xmc,
             const float* __restrict__ dbl, const float* __restrict__ xz,
             const float* __restrict__ A_log, const float* __restrict__ Dp,
             const float* __restrict__ hin, unsigned short* __restrict__ g_out)
{
  const int d = blockIdx.x * 64 + threadIdx.x;
  const int b = blockIdx.y;
  const int c = blockIdx.z;
  float A[16], h[16];
  size_t base = (((size_t)c * 4 + b) * 1536 + d) * 16;
  #pragma unroll
  for (int n = 0; n < 16; ++n) {
    A[n] = -__expf(A_log[d * 16 + n]);
    h[n] = hin[base + n];
  }
  const float Dd = Dp[d];
  const int t0 = c * 125;
  for (int t = t0; t < t0 + 125; ++t) {
    size_t r = (size_t)b * 1000 + t;
    float dtv = dt[r * 1536 + d];
    float xv  = xmc[r * 1536 + d];
    float zv  = xz[r * 3072 + 1536 + d];
    const float* bc = dbl + r * 80;
    float dtx = dtv * xv;
    float y = 0.f;
    #pragma unroll
    for (int n = 0; n < 16; ++n) {
      float hn = fmaf(__expf(dtv * A[n]), h[n], dtx * bc[48 + n]);
      h[n] = hn;
      y = fmaf(hn, bc[64 + n], y);
    }
    y = fmaf(xv, Dd, y);
    g_out[r * 1536 + d] = f2bf(y * (zv * sigmoidf_(zv)));
  }
}

// ---------------------------------------------------------------------------
extern "C" void kernel_launch(void* const* d_in, const int* in_sizes, int n_in,
                              void* d_out, int out_size, void* d_ws, size_t ws_size,
                              hipStream_t stream)
{
  const float* x    = (const float*)d_in[0];
  const float* cw1[4] = {(const float*)d_in[1],  (const float*)d_in[7],
                         (const float*)d_in[13], (const float*)d_in[19]};
  const float* cg1[4] = {(const float*)d_in[2],  (const float*)d_in[8],
                         (const float*)d_in[14], (const float*)d_in[20]};
  const float* cb1[4] = {(const float*)d_in[3],  (const float*)d_in[9],
                         (const float*)d_in[15], (const float*)d_in[21]};
  const float* cw2[4] = {(const float*)d_in[4],  (const float*)d_in[10],
                         (const float*)d_in[16], (const float*)d_in[22]};
  const float* cg2[4] = {(const float*)d_in[5],  (const float*)d_in[11],
                         (const float*)d_in[17], (const float*)d_in[23]};
  const float* cb2[4] = {(const float*)d_in[6],  (const float*)d_in[12],
                         (const float*)d_in[18], (const float*)d_in[24]};
  const float* fc5w = (const float*)d_in[25]; const float* bn5g = (const float*)d_in[26]; const float* bn5b = (const float*)d_in[27];
  const float* lng  = (const float*)d_in[28]; const float* lnb  = (const float*)d_in[29];
  const float* minw = (const float*)d_in[30]; const float* mcw  = (const float*)d_in[31]; const float* mcb  = (const float*)d_in[32];
  const float* mxw  = (const float*)d_in[33]; const float* mdtw = (const float*)d_in[34]; const float* mdtb = (const float*)d_in[35];
  const float* malog= (const float*)d_in[36]; const float* mD   = (const float*)d_in[37]; const float* moutw= (const float*)d_in[38];
  const float* pw   = (const float*)d_in[39]; const float* pb   = (const float*)d_in[40];

  char* ws = (char*)d_ws;
  // conv phase:
  unsigned short* bufA = (unsigned short*)(ws + 0);            // 30 MB
  unsigned short* bufB = (unsigned short*)(ws + 30000000);     // 30 MB
  unsigned short* w1b = (unsigned short*)(ws + 60000000);
  unsigned short* w2a = (unsigned short*)(ws + 60100000);
  unsigned short* w2b = (unsigned short*)(ws + 60200000);
  unsigned short* w3a = (unsigned short*)(ws + 60300000);
  unsigned short* w3b = (unsigned short*)(ws + 60450000);
  unsigned short* w4a = (unsigned short*)(ws + 60650000);
  unsigned short* w4b = (unsigned short*)(ws + 60900000);
  unsigned short* fc5w_bf = (unsigned short*)(ws + 61500000);  // 768*1792
  unsigned short* minw_bf = (unsigned short*)(ws + 64300000);  // 3072*768
  unsigned short* feat_bf = (unsigned short*)(ws + 69100000);  // [4000][1792] bf16
  float*          hfc     = (float*)(ws + 83500000);           // [4000][768] f32
  unsigned short* hln     = (unsigned short*)(ws + 95900000);  // [4000][768] bf16
  unsigned short* moutw_bf= (unsigned short*)(ws + 102200000); // 768*1536
  float*          hend    = (float*)(ws + 104700000);          // 8*4*1536*16 f32
  float*          pend    = (float*)(ws + 107900000);
  float*          hin     = (float*)(ws + 111100000);
  unsigned short* gbf     = (unsigned short*)(ws + 114300000); // [4000][1536] bf16
  // post-conv fp32 (over dead conv regions):
  float* xzb  = (float*)(ws + 0);                              // [4000][3072]
  float* xmc  = (float*)(ws + 49200000);                       // [4000][1536]
  float* dblb = (float*)(ws + 74000000);                       // [4000][80]
  float* dtb  = (float*)(ws + 75500000);                       // [4000][1536]
  float* mam  = (float*)(ws + 83500000);                       // [4000][768] (hfc dead)

  dim3 blk(256);

  // ---- weight conversions (conv 3x3 + GEMM weights) ----
  {
    struct WT { const float* src; unsigned short* dst; int CO, CIN, COp, Cpin; };
    WT wt[7] = {
      {cw2[0], w1b,  48,  48,  64,  64},
      {cw1[1], w2a,  64,  48,  64,  64},
      {cw2[1], w2b,  64,  64,  64,  64},
      {cw1[2], w3a,  96,  64,  96,  64},
      {cw2[2], w3b,  96,  96,  96,  96},
      {cw1[3], w4a, 128,  96, 128,  96},
      {cw2[3], w4b, 128, 128, 128, 128},
    };
    for (int i = 0; i < 7; ++i) {
      int total = 9 * wt[i].COp * wt[i].Cpin;
      wt_transform<<<dim3((total + 255) / 256), blk, 0, stream>>>(
          wt[i].src, wt[i].dst, wt[i].CO, wt[i].CIN, wt[i].COp, wt[i].Cpin, total);
    }
    wcvt<<<dim3((1376256 + 255) / 256), blk, 0, stream>>>(fc5w, fc5w_bf, 1376256);
    wcvt<<<dim3((2359296 + 255) / 256), blk, 0, stream>>>(minw, minw_bf, 2359296);
    wcvt<<<dim3((1179648 + 255) / 256), blk, 0, stream>>>(moutw, moutw_bf, 1179648);
  }

  auto zb = [&](unsigned short* buf, int F, int Cp) {
    int total = 2 * (F + 2) * Cp + 2000 * Cp;
    zero_border<<<dim3((total + 255) / 256), blk, 0, stream>>>(buf, F, Cp, total);
  };
  auto pool = [&](const unsigned short* in, unsigned short* out,
                  int Fin, int Fo, int Cp) {
    int total4 = 1000 * Fo * Cp / 4;
    pool_ch<<<dim3((total4 + 255) / 256), blk, 0, stream>>>(in, out, Fin, Fo, Cp, total4);
  };

  for (int b = 0; b < 4; ++b) {
    const float* xb = x + (size_t)b * 1000 * 229;
    zb(bufA, 229, 64);
    conv1_first<<<dim3(58, 1000), blk, 0, stream>>>(xb, cw1[0], cg1[0], cb1[0], bufA);
    zb(bufB, 229, 64);
    conv_mfma<64, 64, 229, 128, 48><<<dim3(1790), blk, 0, stream>>>(
        bufA, w1b, cg2[0], cb2[0], bufB, 229000);
    zb(bufA, 114, 64);
    pool(bufB, bufA, 229, 114, 64);
    zb(bufB, 114, 64);
    conv_mfma<64, 64, 114, 128, 64><<<dim3(891), blk, 0, stream>>>(
        bufA, w2a, cg1[1], cb1[1], bufB, 114000);
    zb(bufA, 114, 64);
    conv_mfma<64, 64, 114, 128, 64><<<dim3(891), blk, 0, stream>>>(
        bufB, w2b, cg2[1], cb2[1], bufA, 114000);
    zb(bufB, 57, 64);
    pool(bufA, bufB, 114, 57, 64);
    zb(bufA, 57, 96);
    conv_mfma<96, 64, 57, 128, 96><<<dim3(446), blk, 0, stream>>>(
        bufB, w3a, cg1[2], cb1[2], bufA, 57000);
    zb(bufB, 57, 96);
    conv_mfma<96, 96, 57, 128, 96><<<dim3(446), blk, 0, stream>>>(
        bufA, w3b, cg2[2], cb2[2], bufB, 57000);
    zb(bufA, 28, 96);
    pool(bufB, bufA, 57, 28, 96);
    zb(bufB, 28, 128);
    conv_mfma<128, 96, 28, 64, 128><<<dim3(438), blk, 0, stream>>>(
        bufA, w4a, cg1[3], cb1[3], bufB, 28000);
    zb(bufA, 28, 128);
    conv_mfma<128, 128, 28, 64, 128><<<dim3(438), blk, 0, stream>>>(
        bufB, w4b, cg2[3], cb2[3], bufA, 28000);
    pool4_trans<<<dim3((1000 * 128 * 14 + 255) / 256), blk, 0, stream>>>(
        bufA, feat_bf, b * 1000);
  }

  // ---- fc5 + BN + ReLU (bf16 MFMA) ----
  gemm_bf16<1><<<dim3(12, 32), blk, 0, stream>>>(feat_bf, 1792, fc5w_bf, hfc, 4000, 768, 1792, bn5g, bn5b);
  // ---- LayerNorm -> bf16 ----
  layernorm768_bf<<<dim3(4000), blk, 0, stream>>>(hfc, lng, lnb, hln);
  // ---- mamba in_proj (bf16 MFMA) ----
  gemm_bf16<0><<<dim3(48, 32), blk, 0, stream>>>(hln, 768, minw_bf, xzb, 4000, 3072, 768, nullptr, nullptr);
  // ---- depthwise causal conv + silu ----
  dwconv_silu<<<dim3((6144000 + 255) / 256), blk, 0, stream>>>(xzb, mcw, mcb, xmc, 6144000);
  // ---- x_proj (fp32) ----
  gemm_nt<0><<<dim3(2, 63), blk, 0, stream>>>(xmc, 1536, mxw, dblb, 4000, 80, 1536, nullptr, nullptr);
  // ---- dt = softplus(dbl[:, :48] @ dt_w^T + dt_b) (fp32) ----
  gemm_nt<2><<<dim3(24, 63), blk, 0, stream>>>(dblb, 80, mdtw, dtb, 4000, 1536, 48, nullptr, mdtb);
  // ---- chunked parallel scan (NC=8, L=125) -> gbf (bf16) ----
  scan_p1<<<dim3(24, 4, 8), dim3(64), 0, stream>>>(dtb, xmc, dblb, malog, hend, pend);
  scan_p2<<<dim3(24), blk, 0, stream>>>(hend, pend, hin);
  scan_p3<<<dim3(24, 4, 8), dim3(64), 0, stream>>>(dtb, xmc, dblb, xzb, malog, mD, hin, gbf);
  // ---- out_proj (bf16 MFMA) ----
  gemm_bf16<0><<<dim3(12, 32), blk, 0, stream>>>(gbf, 1536, moutw_bf, mam, 4000, 768, 1536, nullptr, nullptr);
  // ---- final proj + sigmoid -> d_out (fp32) ----
  gemm_nt<3><<<dim3(2, 63), blk, 0, stream>>>(mam, 768, pw, (float*)d_out, 4000, 88, 768, nullptr, pb);
}

// Round 11
// 1739.445 us; speedup vs baseline: 5.2007x; 1.2120x over previous
//
#include <hip/hip_runtime.h>
#include <math.h>

// ---------------------------------------------------------------------------
// Round 11: (1) ALL GEMMs -> bf16 MFMA (x_proj N-pad 128, dt K-pad 64, final
// proj N-pad 128 + sigmoid; gemm_nt deleted); (2) conv L2-L4 batched over the
// 4 batch elements via grid.z; (3) zero_border once per buffer; static memory
// re-map, peak ~126.1 MB.
// ---------------------------------------------------------------------------

static __device__ __forceinline__ float sigmoidf_(float x) {
  return 1.f / (1.f + __expf(-x));
}
static __device__ __forceinline__ unsigned short f2bf(float f) {
  union { float f; unsigned int u; } c; c.f = f;
  unsigned int u = c.u;
  unsigned int r = (u + 0x7FFFu + ((u >> 16) & 1u)) >> 16;   // RTNE
  return (unsigned short)r;
}
static __device__ __forceinline__ float bf2f(unsigned short b) {
  union { unsigned int u; float f; } c; c.u = ((unsigned int)b) << 16;
  return c.f;
}
static __device__ __forceinline__ void glds16(const void* g, void* l) {
  __builtin_amdgcn_global_load_lds(
      (const __attribute__((address_space(1))) unsigned int*)g,
      (__attribute__((address_space(3))) unsigned int*)l, 16, 0, 0);
}

typedef __attribute__((ext_vector_type(8))) short short8b;
typedef __attribute__((ext_vector_type(4))) float f32x4;
typedef __attribute__((ext_vector_type(4))) unsigned short ushort4b;

// ---------------- zero padded borders (nb batches) -------------------------
__global__ __launch_bounds__(256)
void zero_border(unsigned short* __restrict__ buf, int F, int Cp, int totalPB,
                 int nb, int bstride)
{
  int idx = blockIdx.x * 256 + threadIdx.x;
  if (idx >= totalPB * nb) return;
  int b = idx / totalPB;
  int k = idx % totalPB;
  unsigned short* p = buf + (size_t)b * bstride;
  int rowelems = (F + 2) * Cp;
  if (k < 2 * rowelems) {
    int r = k / rowelems;
    int e = k % rowelems;
    p[(size_t)(r * 1001) * rowelems + e] = 0;
  } else {
    int j = k - 2 * rowelems;
    int t = j / (2 * Cp) + 1;
    int side = (j / Cp) & 1;
    int c = j % Cp;
    p[((size_t)t * (F + 2) + (side ? F + 1 : 0)) * Cp + c] = 0;
  }
}

// ---------------- weight transform: [CO][CIN][3][3] f32 -> [9][COp][Cpin] bf16
__global__ __launch_bounds__(256)
void wt_transform(const float* __restrict__ W, unsigned short* __restrict__ dst,
                  int CO, int CIN, int COp, int Cpin, int total)
{
  int idx = blockIdx.x * 256 + threadIdx.x;
  if (idx >= total) return;
  int ci = idx % Cpin;
  int co = (idx / Cpin) % COp;
  int s  = idx / (Cpin * COp);
  float v = (co < CO && ci < CIN) ? W[((size_t)co * CIN + ci) * 9 + s] : 0.f;
  dst[idx] = f2bf(v);
}

// ---------------- GEMM-weight converters -----------------------------------
__global__ __launch_bounds__(256)
void wcvt(const float* __restrict__ src, unsigned short* __restrict__ dst, int total)
{
  int i = blockIdx.x * 256 + threadIdx.x;
  if (i < total) dst[i] = f2bf(src[i]);
}
// pad rows: dst [Npad][K], rows >= Nreal zero
__global__ __launch_bounds__(256)
void wpadN(const float* __restrict__ src, unsigned short* __restrict__ dst,
           int Nreal, int Npad, int K)
{
  int idx = blockIdx.x * 256 + threadIdx.x;
  if (idx >= Npad * K) return;
  int n = idx / K, k = idx % K;
  dst[idx] = (n < Nreal) ? f2bf(src[(size_t)n * K + k]) : 0;
}
// pad cols: dst [N][Kpad], cols >= Kreal zero
__global__ __launch_bounds__(256)
void wpadK(const float* __restrict__ src, unsigned short* __restrict__ dst,
           int Kreal, int Kpad, int N)
{
  int idx = blockIdx.x * 256 + threadIdx.x;
  if (idx >= N * Kpad) return;
  int n = idx / Kpad, k = idx % Kpad;
  dst[idx] = (k < Kreal) ? f2bf(src[(size_t)n * Kreal + k]) : 0;
}

// ---------------- first conv (CIN=1) fp32 -> padded bf16 -------------------
__global__ __launch_bounds__(256)
void conv1_first(const float* __restrict__ x, const float* __restrict__ W,
                 const float* __restrict__ g, const float* __restrict__ bt,
                 unsigned short* __restrict__ out)
{
  __shared__ float ws[48 * 9];
  __shared__ float xs[3][6];
  const int tid = threadIdx.x;
  const int f0 = blockIdx.x * 4;
  const int t  = blockIdx.y;
  for (int i = tid; i < 48 * 9; i += 256) ws[i] = W[i];
  if (tid < 18) {
    int r = tid / 6, c = tid % 6;
    int ff = f0 - 1 + c, tt = t - 1 + r;
    xs[r][c] = (ff >= 0 && ff < 229 && tt >= 0 && tt < 1000)
                   ? x[tt * 229 + ff] : 0.f;
  }
  __syncthreads();
  const int co = tid & 63;
  const int fi = tid >> 6;
  const int f  = f0 + fi;
  float v = 0.f;
  if (co < 48) {
    float acc = 0.f;
    #pragma unroll
    for (int ky = 0; ky < 3; ++ky)
      #pragma unroll
      for (int kx = 0; kx < 3; ++kx)
        acc = fmaf(ws[co * 9 + ky * 3 + kx], xs[ky][fi + kx], acc);
    const float inv = rsqrtf(1.f + 1e-5f);
    v = fmaxf(fmaf(acc, g[co] * inv, bt[co]), 0.f);
  }
  if (f < 229)
    out[((size_t)(t + 1) * 231 + f + 1) * 64 + co] = f2bf(v);
}

// ---------------- MFMA shift-GEMM conv3x3 + BN + ReLU (batched) ------------
template<int COp, int Cpin, int F, int BM, int CO>
__global__ __launch_bounds__(256)
void conv_mfma(const unsigned short* __restrict__ act0,
               const unsigned short* __restrict__ W9,
               const float* __restrict__ gam, const float* __restrict__ bet,
               unsigned short* __restrict__ out0, int M,
               int actStride, int outStride)
{
  static_assert(BM == 64 || BM == 128, "");
  constexpr int MI = BM / 32;
  constexpr int NJ = COp / 32;
  constexpr int KSTEPS = Cpin / 32;
  __shared__ alignas(16) short A_s[4 * BM * 8];
  __shared__ alignas(16) short B_s[4 * COp * 8];

  const unsigned short* act = act0 + (size_t)blockIdx.z * actStride;
  unsigned short* out = out0 + (size_t)blockIdx.z * outStride;

  const int tid  = threadIdx.x;
  const int lane = tid & 63, w = tid >> 6;
  const int wm = w >> 1, wn = w & 1;
  const int m0 = blockIdx.x * BM;
  const int wbase = tid & 192;

  int prA[BM / 64];
  #pragma unroll
  for (int j = 0; j < BM / 64; ++j) {
    int slot = j * 256 + tid;
    int row  = slot % BM;
    int pos  = m0 + row; if (pos >= M) pos = M - 1;
    int t = pos / F, f = pos - t * F;
    prA[j] = (t + 1) * (F + 2) + (f + 1);
  }

  f32x4 acc[MI][NJ];
  #pragma unroll
  for (int i = 0; i < MI; ++i)
    #pragma unroll
    for (int jn = 0; jn < NJ; ++jn) acc[i][jn] = (f32x4){0.f, 0.f, 0.f, 0.f};

  for (int s = 0; s < 9; ++s) {
    const int soff = (s / 3 - 1) * (F + 2) + (s % 3) - 1;
    for (int kc = 0; kc < KSTEPS; ++kc) {
      __syncthreads();
      #pragma unroll
      for (int j = 0; j < BM / 64; ++j) {
        int slot = j * 256 + tid;
        int q = slot / BM;
        glds16(&act[(size_t)(prA[j] + soff) * Cpin + kc * 32 + q * 8],
               &A_s[(j * 256 + wbase) * 8]);
      }
      #pragma unroll
      for (int sb = 0; sb < (COp * 4 + 255) / 256; ++sb) {
        int slot = sb * 256 + tid;
        if (slot < COp * 4) {
          int q = slot / COp, co = slot % COp;
          glds16(&W9[((size_t)(s * COp + co)) * Cpin + kc * 32 + q * 8],
                 &B_s[(sb * 256 + wbase) * 8]);
        }
      }
      __syncthreads();
      const int lr = lane & 15, lq = lane >> 4;
      short8b a[MI], b[NJ];
      #pragma unroll
      for (int i = 0; i < MI; ++i)
        a[i] = *(const short8b*)&A_s[(lq * BM + wm * (BM / 2) + i * 16 + lr) * 8];
      #pragma unroll
      for (int jn = 0; jn < NJ; ++jn)
        b[jn] = *(const short8b*)&B_s[(lq * COp + wn * (COp / 2) + jn * 16 + lr) * 8];
      #pragma unroll
      for (int i = 0; i < MI; ++i)
        #pragma unroll
        for (int jn = 0; jn < NJ; ++jn)
          acc[i][jn] = __builtin_amdgcn_mfma_f32_16x16x32_bf16(
              a[i], b[jn], acc[i][jn], 0, 0, 0);
    }
  }
  const float inv = rsqrtf(1.f + 1e-5f);
  const int lr = lane & 15, lq = lane >> 4;
  #pragma unroll
  for (int jn = 0; jn < NJ; ++jn) {
    int co = wn * (COp / 2) + jn * 16 + lr;
    float sc = (co < CO) ? gam[co] * inv : 0.f;
    float bi = (co < CO) ? bet[co] : 0.f;
    #pragma unroll
    for (int i = 0; i < MI; ++i) {
      #pragma unroll
      for (int r = 0; r < 4; ++r) {
        int pos = m0 + wm * (BM / 2) + i * 16 + lq * 4 + r;
        if (pos < M) {
          int t = pos / F, f = pos - t * F;
          float v = fmaxf(fmaf(acc[i][jn][r], sc, bi), 0.f);
          out[((size_t)(t + 1) * (F + 2) + f + 1) * COp + co] = f2bf(v);
        }
      }
    }
  }
}

// ---------------- avg-pool /2 along F, padded bf16 -> padded bf16 (batched)-
__global__ __launch_bounds__(256)
void pool_ch(const unsigned short* __restrict__ in0, unsigned short* __restrict__ out0,
             int Fin, int Fo, int Cp, int total4, int inStride, int outStride)
{
  int idx = blockIdx.x * 256 + threadIdx.x;
  if (idx >= total4) return;
  const unsigned short* in = in0 + (size_t)blockIdx.z * inStride;
  unsigned short* out = out0 + (size_t)blockIdx.z * outStride;
  int cg = Cp / 4;
  int c4 = idx % cg;
  int fo = (idx / cg) % Fo;
  int t  = idx / (cg * Fo);
  size_t bi = ((size_t)(t + 1) * (Fin + 2) + 2 * fo + 1) * Cp + c4 * 4;
  ushort4b a = *(const ushort4b*)&in[bi];
  ushort4b b = *(const ushort4b*)&in[bi + Cp];
  ushort4b o;
  #pragma unroll
  for (int e = 0; e < 4; ++e)
    o[e] = f2bf((bf2f(a[e]) + bf2f(b[e])) * 0.5f);
  *(ushort4b*)&out[((size_t)(t + 1) * (Fo + 2) + fo + 1) * Cp + c4 * 4] = o;
}

// ---------------- final pool -> transposed bf16 features (batched) ---------
__global__ __launch_bounds__(256)
void pool4_trans(const unsigned short* __restrict__ in0,
                 unsigned short* __restrict__ feat, int inStride)
{
  int idx = blockIdx.x * 256 + threadIdx.x;
  if (idx >= 1000 * 128 * 14) return;
  const unsigned short* in = in0 + (size_t)blockIdx.z * inStride;
  int boff = blockIdx.z * 1000;
  int fo = idx % 14;
  int co = (idx / 14) % 128;
  int t  = idx / (14 * 128);
  size_t bi = ((size_t)(t + 1) * 30 + 2 * fo + 1) * 128 + co;
  float v = (bf2f(in[bi]) + bf2f(in[bi + 128])) * 0.5f;
  feat[((size_t)(boff + t)) * 1792 + co * 14 + fo] = f2bf(v);
}

// ---------------- bf16 MFMA GEMM (global_load_lds) -------------------------
// C[M,Nout] = A[M,K](bf16) * W[N,K]^T(bf16). BM=128,BN=64,BK=32.
// K%32==0, N%64==0 (padded). EPI: 0 none; 1 BN+relu; 2 softplus+bias;
// 3 sigmoid+bias. Writes fp32 C (if OUTF32) and/or bf16 Cbf (if OUTBF),
// both with leading dim ldc, cols < Nout only.
template<int EPI, bool OUTF32, bool OUTBF>
__global__ __launch_bounds__(256)
void gemm_bf16(const unsigned short* __restrict__ A, int lda,
               const unsigned short* __restrict__ W,
               float* __restrict__ C, unsigned short* __restrict__ Cbf,
               int M, int Nout, int ldc, int K,
               const float* __restrict__ sc, const float* __restrict__ bi)
{
  __shared__ alignas(16) short A_s[4 * 128 * 8];
  __shared__ alignas(16) short B_s[4 * 64 * 8];
  const int tid  = threadIdx.x;
  const int lane = tid & 63, w = tid >> 6;
  const int wm = w >> 1, wn = w & 1;
  const int m0 = blockIdx.y * 128, n0 = blockIdx.x * 64;
  const int wbase = tid & 192;

  int mrow[2];
  #pragma unroll
  for (int j = 0; j < 2; ++j) {
    int slot = j * 256 + tid;
    int row = slot & 127;
    int m = m0 + row; if (m >= M) m = M - 1;
    mrow[j] = m;
  }
  const int bq = tid >> 6, bn = tid & 63;

  f32x4 acc[4][2];
  #pragma unroll
  for (int i = 0; i < 4; ++i)
    #pragma unroll
    for (int jn = 0; jn < 2; ++jn) acc[i][jn] = (f32x4){0.f, 0.f, 0.f, 0.f};

  for (int k0 = 0; k0 < K; k0 += 32) {
    __syncthreads();
    #pragma unroll
    for (int j = 0; j < 2; ++j) {
      int slot = j * 256 + tid;
      int q = slot >> 7;
      glds16(&A[(size_t)mrow[j] * lda + k0 + q * 8],
             &A_s[(j * 256 + wbase) * 8]);
    }
    glds16(&W[(size_t)(n0 + bn) * K + k0 + bq * 8], &B_s[wbase * 8]);
    __syncthreads();
    const int lr = lane & 15, lq = lane >> 4;
    short8b a[4], b[2];
    #pragma unroll
    for (int i = 0; i < 4; ++i)
      a[i] = *(const short8b*)&A_s[(lq * 128 + wm * 64 + i * 16 + lr) * 8];
    #pragma unroll
    for (int jn = 0; jn < 2; ++jn)
      b[jn] = *(const short8b*)&B_s[(lq * 64 + wn * 32 + jn * 16 + lr) * 8];
    #pragma unroll
    for (int i = 0; i < 4; ++i)
      #pragma unroll
      for (int jn = 0; jn < 2; ++jn)
        acc[i][jn] = __builtin_amdgcn_mfma_f32_16x16x32_bf16(
            a[i], b[jn], acc[i][jn], 0, 0, 0);
  }
  const float inv = rsqrtf(1.f + 1e-5f);
  const int lr = lane & 15, lq = lane >> 4;
  #pragma unroll
  for (int jn = 0; jn < 2; ++jn) {
    int col = n0 + wn * 32 + jn * 16 + lr;
    if (col >= Nout) continue;
    float scv = (EPI == 1) ? sc[col] * inv : 0.f;
    float biv = (EPI == 1 || EPI == 2 || EPI == 3) ? (bi ? bi[col] : 0.f) : 0.f;
    #pragma unroll
    for (int i = 0; i < 4; ++i) {
      #pragma unroll
      for (int r = 0; r < 4; ++r) {
        int row = m0 + wm * 64 + i * 16 + lq * 4 + r;
        if (row < M) {
          float v = acc[i][jn][r];
          if (EPI == 1) v = fmaxf(fmaf(v, scv, biv), 0.f);
          else if (EPI == 2) {
            float xx = v + biv;
            v = (xx > 20.f) ? xx : log1pf(__expf(xx));
          } else if (EPI == 3) {
            v = sigmoidf_(v + biv);
          }
          if (OUTF32) C[(size_t)row * ldc + col] = v;
          if (OUTBF)  Cbf[(size_t)row * ldc + col] = f2bf(v);
        }
      }
    }
  }
}

// ---------------- LayerNorm over 768 features, bf16 out --------------------
__global__ __launch_bounds__(256)
void layernorm768_bf(const float* __restrict__ in, const float* __restrict__ g,
                     const float* __restrict__ b, unsigned short* __restrict__ out)
{
  const int row = blockIdx.x;
  const float* x = in + (size_t)row * 768;
  const int tid = threadIdx.x;
  float v0 = x[tid], v1 = x[tid + 256], v2 = x[tid + 512];
  float s = v0 + v1 + v2;
  float q = v0 * v0 + v1 * v1 + v2 * v2;
  #pragma unroll
  for (int off = 32; off >= 1; off >>= 1) {
    s += __shfl_down(s, off);
    q += __shfl_down(q, off);
  }
  __shared__ float rs[4], rq[4];
  int wave = tid >> 6;
  if ((tid & 63) == 0) { rs[wave] = s; rq[wave] = q; }
  __syncthreads();
  float ts = rs[0] + rs[1] + rs[2] + rs[3];
  float tq = rq[0] + rq[1] + rq[2] + rq[3];
  float mu = ts * (1.f / 768.f);
  float var = tq * (1.f / 768.f) - mu * mu;
  float rstd = rsqrtf(var + 1e-5f);
  unsigned short* o = out + (size_t)row * 768;
  o[tid]       = f2bf((v0 - mu) * rstd * g[tid]       + b[tid]);
  o[tid + 256] = f2bf((v1 - mu) * rstd * g[tid + 256] + b[tid + 256]);
  o[tid + 512] = f2bf((v2 - mu) * rstd * g[tid + 512] + b[tid + 512]);
}

// ---------------- depthwise causal conv (K=4) + SiLU; fp32 + bf16 out ------
__global__ __launch_bounds__(256)
void dwconv_silu(const float* __restrict__ xz, const float* __restrict__ cw,
                 const float* __restrict__ cb, float* __restrict__ xmc,
                 unsigned short* __restrict__ xmc_bf, int total)
{
  int idx = blockIdx.x * 256 + threadIdx.x;
  if (idx >= total) return;
  int d = idx % 1536;
  int t = (idx / 1536) % 1000;
  int b = idx / (1536 * 1000);
  float acc = cb[d];
  #pragma unroll
  for (int j = 0; j < 4; ++j) {
    int tt = t - 3 + j;
    if (tt >= 0)
      acc = fmaf(cw[d * 4 + j], xz[((size_t)(b * 1000 + tt)) * 3072 + d], acc);
  }
  float v = acc * sigmoidf_(acc);
  xmc[idx] = v;
  xmc_bf[idx] = f2bf(v);
}

// ---------------- chunked parallel scan (3 passes, NC=8, L=125) ------------
// dbl stride 128 (padded x_proj output): cols 48-63 = B, 64-79 = C.
__global__ __launch_bounds__(64)
void scan_p1(const float* __restrict__ dt, const float* __restrict__ xmc,
             const float* __restrict__ dbl, const float* __restrict__ A_log,
             float* __restrict__ hend, float* __restrict__ pend)
{
  const int d = blockIdx.x * 64 + threadIdx.x;
  const int b = blockIdx.y;
  const int c = blockIdx.z;
  float A[16], h[16];
  #pragma unroll
  for (int n = 0; n < 16; ++n) {
    A[n] = -__expf(A_log[d * 16 + n]);
    h[n] = 0.f;
  }
  float S = 0.f;
  const int t0 = c * 125;
  for (int t = t0; t < t0 + 125; ++t) {
    size_t r = (size_t)b * 1000 + t;
    float dtv = dt[r * 1536 + d];
    float xv  = xmc[r * 1536 + d];
    const float* bc = dbl + r * 128;
    float dtx = dtv * xv;
    S += dtv;
    #pragma unroll
    for (int n = 0; n < 16; ++n)
      h[n] = fmaf(__expf(dtv * A[n]), h[n], dtx * bc[48 + n]);
  }
  size_t base = (((size_t)c * 4 + b) * 1536 + d) * 16;
  #pragma unroll
  for (int n = 0; n < 16; ++n) {
    hend[base + n] = h[n];
    pend[base + n] = __expf(S * A[n]);
  }
}

__global__ __launch_bounds__(256)
void scan_p2(const float* __restrict__ hend, const float* __restrict__ pend,
             float* __restrict__ hin)
{
  int gid = blockIdx.x * 256 + threadIdx.x;
  if (gid >= 6144) return;
  float cur[16];
  #pragma unroll
  for (int n = 0; n < 16; ++n) cur[n] = 0.f;
  for (int c = 0; c < 8; ++c) {
    size_t base = ((size_t)c * 6144 + gid) * 16;
    #pragma unroll
    for (int n = 0; n < 16; ++n) {
      hin[base + n] = cur[n];
      cur[n] = fmaf(pend[base + n], cur[n], hend[base + n]);
    }
  }
}

__global__ __launch_bounds__(64)
void scan_p3(const float* __restrict__ dt, const float* __restrict__ xmc,
             const float* __restrict__ dbl, const float* __restrict__ xz,
             const float* __restrict__ A_log, const float* __restrict__ Dp,
             const float* __restrict__ hin, unsigned short* __restrict__ g_out)
{
  const int d = blockIdx.x * 64 + threadIdx.x;
  const int b = blockIdx.y;
  const int c = blockIdx.z;
  float A[16], h[16];
  size_t base = (((size_t)c * 4 + b) * 1536 + d) * 16;
  #pragma unroll
  for (int n = 0; n < 16; ++n) {
    A[n] = -__expf(A_log[d * 16 + n]);
    h[n] = hin[base + n];
  }
  const float Dd = Dp[d];
  const int t0 = c * 125;
  for (int t = t0; t < t0 + 125; ++t) {
    size_t r = (size_t)b * 1000 + t;
    float dtv = dt[r * 1536 + d];
    float xv  = xmc[r * 1536 + d];
    float zv  = xz[r * 3072 + 1536 + d];
    const float* bc = dbl + r * 128;
    float dtx = dtv * xv;
    float y = 0.f;
    #pragma unroll
    for (int n = 0; n < 16; ++n) {
      float hn = fmaf(__expf(dtv * A[n]), h[n], dtx * bc[48 + n]);
      h[n] = hn;
      y = fmaf(hn, bc[64 + n], y);
    }
    y = fmaf(xv, Dd, y);
    g_out[r * 1536 + d] = f2bf(y * (zv * sigmoidf_(zv)));
  }
}

// ---------------------------------------------------------------------------
extern "C" void kernel_launch(void* const* d_in, const int* in_sizes, int n_in,
                              void* d_out, int out_size, void* d_ws, size_t ws_size,
                              hipStream_t stream)
{
  const float* x    = (const float*)d_in[0];
  const float* cw1[4] = {(const float*)d_in[1],  (const float*)d_in[7],
                         (const float*)d_in[13], (const float*)d_in[19]};
  const float* cg1[4] = {(const float*)d_in[2],  (const float*)d_in[8],
                         (const float*)d_in[14], (const float*)d_in[20]};
  const float* cb1[4] = {(const float*)d_in[3],  (const float*)d_in[9],
                         (const float*)d_in[15], (const float*)d_in[21]};
  const float* cw2[4] = {(const float*)d_in[4],  (const float*)d_in[10],
                         (const float*)d_in[16], (const float*)d_in[22]};
  const float* cg2[4] = {(const float*)d_in[5],  (const float*)d_in[11],
                         (const float*)d_in[17], (const float*)d_in[23]};
  const float* cb2[4] = {(const float*)d_in[6],  (const float*)d_in[12],
                         (const float*)d_in[18], (const float*)d_in[24]};
  const float* fc5w = (const float*)d_in[25]; const float* bn5g = (const float*)d_in[26]; const float* bn5b = (const float*)d_in[27];
  const float* lng  = (const float*)d_in[28]; const float* lnb  = (const float*)d_in[29];
  const float* minw = (const float*)d_in[30]; const float* mcw  = (const float*)d_in[31]; const float* mcb  = (const float*)d_in[32];
  const float* mxw  = (const float*)d_in[33]; const float* mdtw = (const float*)d_in[34]; const float* mdtb = (const float*)d_in[35];
  const float* malog= (const float*)d_in[36]; const float* mD   = (const float*)d_in[37]; const float* moutw= (const float*)d_in[38];
  const float* pw   = (const float*)d_in[39]; const float* pb   = (const float*)d_in[40];

  char* ws = (char*)d_ws;
  // ---- conv phase (batched L2-L4); strides in bf16 elements ----
  const int S1 = 1002 * 116 * 64;   // 7,438,848  (F=114 padded)
  const int S2 = 1002 * 59 * 64;    // 3,783,552  (F=57)
  const int S3 = 1002 * 59 * 96;    // 5,675,328
  const int S4 = 1002 * 30 * 96;    // 2,885,760  (F=28)
  const int S5 = 1002 * 30 * 128;   // 3,847,680
  unsigned short* bufA   = (unsigned short*)(ws + 0);           // L1 per-batch
  unsigned short* bufB   = (unsigned short*)(ws + 29700000);
  unsigned short* P1out  = (unsigned short*)(ws + 60000000);    // 4x S1
  unsigned short* L2buf  = (unsigned short*)(ws + 0);           // 4x S1
  unsigned short* L2bufB = (unsigned short*)(ws + 60000000);    // 4x S1
  unsigned short* P2out  = (unsigned short*)(ws + 0);           // 4x S2
  unsigned short* L3buf  = (unsigned short*)(ws + 31000000);    // 4x S3
  unsigned short* L3buf2 = (unsigned short*)(ws + 76500000);    // 4x S3
  unsigned short* P3out  = (unsigned short*)(ws + 0);           // 4x S4
  unsigned short* L4buf  = (unsigned short*)(ws + 24000000);    // 4x S5
  unsigned short* L4buf2 = (unsigned short*)(ws + 55000000);    // 4x S5
  unsigned short* w1b = (unsigned short*)(ws + 122000000);
  unsigned short* w2a = (unsigned short*)(ws + 122100000);
  unsigned short* w2b = (unsigned short*)(ws + 122200000);
  unsigned short* w3a = (unsigned short*)(ws + 122300000);
  unsigned short* w3b = (unsigned short*)(ws + 122450000);
  unsigned short* w4a = (unsigned short*)(ws + 122650000);
  unsigned short* w4b = (unsigned short*)(ws + 122900000);
  unsigned short* feat_bf = (unsigned short*)(ws + 86000000);   // [4000][1792]
  // ---- post-conv static map (sequential sharing verified) ----
  float*          hfc      = (float*)(ws + 0);                  // fc5->LN
  float*          xzb      = (float*)(ws + 0);                  // in_proj->p3
  float*          xmc      = (float*)(ws + 49200000);           // dwconv->p3
  unsigned short* minw_bf  = (unsigned short*)(ws + 73800000);  // ->in_proj
  unsigned short* hln      = (unsigned short*)(ws + 78600000);  // LN->in_proj
  float*          dtb      = (float*)(ws + 73800000);           // dt->p3
  unsigned short* xmc_bf   = (unsigned short*)(ws + 98400000);  // dwconv->x_proj
  unsigned short* gbf      = (unsigned short*)(ws + 98400000);  // p3->out_proj
  float*          dblb     = (float*)(ws + 110700000);          // x_proj->p3
  unsigned short* dblb_bf  = (unsigned short*)(ws + 112800000); // x_proj->dt
  unsigned short* dtw_bf   = (unsigned short*)(ws + 113900000); // ->dt
  float*          hend     = (float*)(ws + 113900000);          // p1->p2
  unsigned short* mam_bf   = (unsigned short*)(ws + 113900000); // out_proj->final
  unsigned short* xprojw_bf= (unsigned short*)(ws + 117100000); // ->x_proj
  float*          pend     = (float*)(ws + 117100000);          // p1->p2
  unsigned short* fc5w_bf  = (unsigned short*)(ws + 120300000); // ->fc5
  float*          hin      = (float*)(ws + 120300000);          // p2->p3
  unsigned short* moutw_bf = (unsigned short*)(ws + 123500000); // ->out_proj
  unsigned short* pw_bf    = (unsigned short*)(ws + 125900000); // ->final

  dim3 blk(256);

  // ---- conv weight transforms ----
  {
    struct WT { const float* src; unsigned short* dst; int CO, CIN, COp, Cpin; };
    WT wt[7] = {
      {cw2[0], w1b,  48,  48,  64,  64},
      {cw1[1], w2a,  64,  48,  64,  64},
      {cw2[1], w2b,  64,  64,  64,  64},
      {cw1[2], w3a,  96,  64,  96,  64},
      {cw2[2], w3b,  96,  96,  96,  96},
      {cw1[3], w4a, 128,  96, 128,  96},
      {cw2[3], w4b, 128, 128, 128, 128},
    };
    for (int i = 0; i < 7; ++i) {
      int total = 9 * wt[i].COp * wt[i].Cpin;
      wt_transform<<<dim3((total + 255) / 256), blk, 0, stream>>>(
          wt[i].src, wt[i].dst, wt[i].CO, wt[i].CIN, wt[i].COp, wt[i].Cpin, total);
    }
  }

  auto zb = [&](unsigned short* buf, int F, int Cp, int nb, int bstride) {
    int totalPB = 2 * (F + 2) * Cp + 2000 * Cp;
    zero_border<<<dim3((totalPB * nb + 255) / 256), blk, 0, stream>>>(
        buf, F, Cp, totalPB, nb, bstride);
  };

  // ---- borders: once per buffer that feeds a conv ----
  zb(bufA,  229, 64, 1, 0);
  zb(P1out, 114, 64, 4, S1);
  zb(L2buf, 114, 64, 4, S1);
  zb(P2out,  57, 64, 4, S2);
  zb(L3buf,  57, 96, 4, S3);
  zb(P3out,  28, 96, 4, S4);
  zb(L4buf,  28, 128, 4, S5);

  // ---- L1 per-batch ----
  for (int b = 0; b < 4; ++b) {
    const float* xb = x + (size_t)b * 1000 * 229;
    conv1_first<<<dim3(58, 1000), blk, 0, stream>>>(xb, cw1[0], cg1[0], cb1[0], bufA);
    conv_mfma<64, 64, 229, 128, 48><<<dim3(1790), blk, 0, stream>>>(
        bufA, w1b, cg2[0], cb2[0], bufB, 229000, 0, 0);
    pool_ch<<<dim3((1000 * 114 * 64 / 4 + 255) / 256), blk, 0, stream>>>(
        bufB, P1out + (size_t)b * S1, 229, 114, 64, 1000 * 114 * 64 / 4, 0, 0);
  }

  // ---- L2-L4 batched (grid.z = 4) ----
  conv_mfma<64, 64, 114, 128, 64><<<dim3(891, 1, 4), blk, 0, stream>>>(
      P1out, w2a, cg1[1], cb1[1], L2buf, 114000, S1, S1);
  conv_mfma<64, 64, 114, 128, 64><<<dim3(891, 1, 4), blk, 0, stream>>>(
      L2buf, w2b, cg2[1], cb2[1], L2bufB, 114000, S1, S1);
  pool_ch<<<dim3((1000 * 57 * 64 / 4 + 255) / 256, 1, 4), blk, 0, stream>>>(
      L2bufB, P2out, 114, 57, 64, 1000 * 57 * 64 / 4, S1, S2);
  conv_mfma<96, 64, 57, 128, 96><<<dim3(446, 1, 4), blk, 0, stream>>>(
      P2out, w3a, cg1[2], cb1[2], L3buf, 57000, S2, S3);
  conv_mfma<96, 96, 57, 128, 96><<<dim3(446, 1, 4), blk, 0, stream>>>(
      L3buf, w3b, cg2[2], cb2[2], L3buf2, 57000, S3, S3);
  pool_ch<<<dim3((1000 * 28 * 96 / 4 + 255) / 256, 1, 4), blk, 0, stream>>>(
      L3buf2, P3out, 57, 28, 96, 1000 * 28 * 96 / 4, S3, S4);
  conv_mfma<128, 96, 28, 64, 128><<<dim3(438, 1, 4), blk, 0, stream>>>(
      P3out, w4a, cg1[3], cb1[3], L4buf, 28000, S4, S5);
  conv_mfma<128, 128, 28, 64, 128><<<dim3(438, 1, 4), blk, 0, stream>>>(
      L4buf, w4b, cg2[3], cb2[3], L4buf2, 28000, S5, S5);
  pool4_trans<<<dim3((1000 * 128 * 14 + 255) / 256, 1, 4), blk, 0, stream>>>(
      L4buf2, feat_bf, S5);

  // ---- GEMM weight conversions (after conv: regions now free) ----
  wcvt<<<dim3((1376256 + 255) / 256), blk, 0, stream>>>(fc5w, fc5w_bf, 1376256);
  wcvt<<<dim3((2359296 + 255) / 256), blk, 0, stream>>>(minw, minw_bf, 2359296);
  wcvt<<<dim3((1179648 + 255) / 256), blk, 0, stream>>>(moutw, moutw_bf, 1179648);
  wpadN<<<dim3((128 * 1536 + 255) / 256), blk, 0, stream>>>(mxw, xprojw_bf, 80, 128, 1536);
  wpadK<<<dim3((1536 * 64 + 255) / 256), blk, 0, stream>>>(mdtw, dtw_bf, 48, 64, 1536);
  wpadN<<<dim3((128 * 768 + 255) / 256), blk, 0, stream>>>(pw, pw_bf, 88, 128, 768);

  // ---- fc5 + BN + ReLU ----
  gemm_bf16<1, true, false><<<dim3(12, 32), blk, 0, stream>>>(
      feat_bf, 1792, fc5w_bf, hfc, nullptr, 4000, 768, 768, 1792, bn5g, bn5b);
  // ---- LayerNorm -> bf16 ----
  layernorm768_bf<<<dim3(4000), blk, 0, stream>>>(hfc, lng, lnb, hln);
  // ---- in_proj ----
  gemm_bf16<0, true, false><<<dim3(48, 32), blk, 0, stream>>>(
      hln, 768, minw_bf, xzb, nullptr, 4000, 3072, 3072, 768, nullptr, nullptr);
  // ---- depthwise causal conv + silu (fp32 + bf16) ----
  dwconv_silu<<<dim3((6144000 + 255) / 256), blk, 0, stream>>>(
      xzb, mcw, mcb, xmc, xmc_bf, 6144000);
  // ---- x_proj (N pad 128; fp32 + bf16 out) ----
  gemm_bf16<0, true, true><<<dim3(2, 32), blk, 0, stream>>>(
      xmc_bf, 1536, xprojw_bf, dblb, dblb_bf, 4000, 128, 128, 1536, nullptr, nullptr);
  // ---- dt = softplus(dbl[:, :48] @ dt_w^T + dt_b)  (K pad 64) ----
  gemm_bf16<2, true, false><<<dim3(24, 32), blk, 0, stream>>>(
      dblb_bf, 128, dtw_bf, dtb, nullptr, 4000, 1536, 1536, 64, nullptr, mdtb);
  // ---- chunked parallel scan -> gbf ----
  scan_p1<<<dim3(24, 4, 8), dim3(64), 0, stream>>>(dtb, xmc, dblb, malog, hend, pend);
  scan_p2<<<dim3(24), blk, 0, stream>>>(hend, pend, hin);
  scan_p3<<<dim3(24, 4, 8), dim3(64), 0, stream>>>(dtb, xmc, dblb, xzb, malog, mD, hin, gbf);
  // ---- out_proj (bf16 out only) ----
  gemm_bf16<0, false, true><<<dim3(12, 32), blk, 0, stream>>>(
      gbf, 1536, moutw_bf, nullptr, mam_bf, 4000, 768, 768, 1536, nullptr, nullptr);
  // ---- final proj + sigmoid -> d_out (N pad 128, Nout 88) ----
  gemm_bf16<3, true, false><<<dim3(2, 32), blk, 0, stream>>>(
      mam_bf, 768, pw_bf, (float*)d_out, nullptr, 4000, 88, 88, 768, nullptr, pb);
}